// Round 1
// baseline (1542.529 us; speedup 1.0000x reference)
//
#include <hip/hip_runtime.h>
#include <math.h>

// Problem constants (from reference)
#define B64  64
#define NN   512
#define FINN 1024
#define HH   128
#define LL   512
#define KK1  256
#define KK2  128
#define KK3  64

// ---------------- wave helpers ----------------
__device__ __forceinline__ float wsum(float v) {
#pragma unroll
    for (int off = 32; off; off >>= 1) v += __shfl_xor(v, off, 64);
    return v;
}

// ---------------- generic fp32 GEMM ----------------
// C[M,N] = A[M,K] @ B[K,N]; optional per-row scale, optional bias+relu.
// BN = 128 fixed, BK = 16, BM = TM*16 (TM = 4 or 8), 256 threads.
template <int TM>
__global__ __launch_bounds__(256) void sgemm_k(
    const float* __restrict__ A, const float* __restrict__ Bm, float* __restrict__ C,
    int M, int N, int K,
    const float* __restrict__ rowscale, const float* __restrict__ bias, int do_relu)
{
    constexpr int BM = TM * 16;
    constexpr int BN = 128;
    constexpr int BK = 16;
    __shared__ float As[BK][BM + 4];   // transposed A tile (k-major)
    __shared__ float Bs[BK][BN + 4];

    const int tid = threadIdx.x;
    const int tx = tid & 15;       // 16 col groups of 8
    const int ty = tid >> 4;       // 16 row groups of TM
    const int m0 = blockIdx.y * BM;
    const int n0 = blockIdx.x * BN;

    float acc[TM][8];
#pragma unroll
    for (int i = 0; i < TM; ++i)
#pragma unroll
        for (int j = 0; j < 8; ++j) acc[i][j] = 0.f;

    for (int k0 = 0; k0 < K; k0 += BK) {
        // stage A tile: BM rows x 16 k  (BM*4 float4s)
#pragma unroll
        for (int i = 0; i < BM / 64; ++i) {
            int li = tid + 256 * i;
            int arow = li >> 2;
            int kq = (li & 3) << 2;
            float4 f = make_float4(0.f, 0.f, 0.f, 0.f);
            if (m0 + arow < M)
                f = *(const float4*)(A + (size_t)(m0 + arow) * K + k0 + kq);
            As[kq + 0][arow] = f.x;
            As[kq + 1][arow] = f.y;
            As[kq + 2][arow] = f.z;
            As[kq + 3][arow] = f.w;
        }
        // stage B tile: 16 x 128
#pragma unroll
        for (int i = 0; i < 2; ++i) {
            int li = tid + 256 * i;
            int brow = li >> 5;
            int bcol = (li & 31) << 2;
            float4 f = *(const float4*)(Bm + (size_t)(k0 + brow) * N + n0 + bcol);
            *(float4*)&Bs[brow][bcol] = f;
        }
        __syncthreads();
#pragma unroll
        for (int kk = 0; kk < BK; ++kk) {
            float a[TM], bf[8];
            *(float4*)&a[0] = *(const float4*)&As[kk][ty * TM];
            if constexpr (TM == 8)
                *(float4*)&a[4] = *(const float4*)&As[kk][ty * TM + 4];
            *(float4*)&bf[0] = *(const float4*)&Bs[kk][tx * 8];
            *(float4*)&bf[4] = *(const float4*)&Bs[kk][tx * 8 + 4];
#pragma unroll
            for (int i = 0; i < TM; ++i)
#pragma unroll
                for (int j = 0; j < 8; ++j)
                    acc[i][j] = fmaf(a[i], bf[j], acc[i][j]);
        }
        __syncthreads();
    }

    // epilogue
#pragma unroll
    for (int i = 0; i < TM; ++i) {
        int r = m0 + ty * TM + i;
        if (r >= M) continue;
        float scale = rowscale ? rowscale[r] : 1.f;
        float out[8];
#pragma unroll
        for (int j = 0; j < 8; ++j) {
            float v = acc[i][j] * scale;
            if (bias) v += bias[n0 + tx * 8 + j];
            if (do_relu) v = fmaxf(v, 0.f);
            out[j] = v;
        }
        float* cp = C + (size_t)r * N + n0 + tx * 8;
        *(float4*)&cp[0] = *(float4*)&out[0];
        *(float4*)&cp[4] = *(float4*)&out[4];
    }
}

// ---------------- adjacency row-sum -> rsqrt(deg) ----------------
// one wave per row; rows = B*n
__global__ __launch_bounds__(256) void rowsum_kernel(
    const float* __restrict__ A, float* __restrict__ dinv, int n)
{
    int wid = (blockIdx.x * blockDim.x + threadIdx.x) >> 6;
    int lane = threadIdx.x & 63;
    const float* Arow = A + (size_t)wid * n;
    float s = 0.f;
    for (int c = lane; c < n; c += 64) s += Arow[c];
    s = wsum(s);
    if (lane == 0) dinv[wid] = (s > 0.f) ? rsqrtf(s) : 0.f;
}

// ---------------- SpMM (binary-ish A) + GCN epilogue + fused score ----------------
// out[b,row,:] = relu( (sum_m A[b,row,m] * Hin[b,m,:]) * dinv[b,row] + bias )
// score[b,row] = tanh( dot(out_row, p) / (pnorm + 1e-12) )
__global__ __launch_bounds__(256) void spmm_gcn(
    const float* __restrict__ A, const float* __restrict__ Hin,
    const float* __restrict__ dinv, const float* __restrict__ bias,
    const float* __restrict__ p, const float* __restrict__ pnorm,
    float* __restrict__ Gout, float* __restrict__ score, int n)
{
    int wid = (blockIdx.x * blockDim.x + threadIdx.x) >> 6;
    int lane = threadIdx.x & 63;
    int b = wid / n, row = wid % n;
    const float* Arow = A + ((size_t)b * n + row) * n;
    float acc0 = 0.f, acc1 = 0.f;
    for (int c = 0; c < n; c += 64) {
        float av = Arow[c + lane];
        unsigned long long mask = __ballot(av != 0.0f);
        while (mask) {
            int i = __ffsll((unsigned long long)mask) - 1;
            mask &= mask - 1;
            float val = __shfl(av, i, 64);
            const float* hr = Hin + ((size_t)b * n + c + i) * HH;
            acc0 = fmaf(val, hr[lane], acc0);
            acc1 = fmaf(val, hr[lane + 64], acc1);
        }
    }
    float dv = dinv[b * n + row];
    float g0 = fmaxf(fmaf(acc0, dv, bias[lane]), 0.f);
    float g1 = fmaxf(fmaf(acc1, dv, bias[lane + 64]), 0.f);
    float* gr = Gout + ((size_t)b * n + row) * HH;
    gr[lane] = g0;
    gr[lane + 64] = g1;
    float s = g0 * p[lane] + g1 * p[lane + 64];
    s = wsum(s);
    if (lane == 0) score[b * n + row] = tanhf(s / (pnorm[0] + 1e-12f));
}

// ---------------- per-batch top-k (bitonic sort, descending, stable ties) --------
__global__ __launch_bounds__(256) void topk_kernel(
    const float* __restrict__ score, int* __restrict__ idx_out, int n, int k)
{
    __shared__ float sv[512];
    __shared__ int si[512];
    int b = blockIdx.x, tid = threadIdx.x;
    for (int j = tid; j < n; j += blockDim.x) { sv[j] = score[b * n + j]; si[j] = j; }
    __syncthreads();
    for (int sz = 2; sz <= n; sz <<= 1) {
        for (int st = sz >> 1; st; st >>= 1) {
            for (int t = tid; t < (n >> 1); t += blockDim.x) {
                int i = ((t / st) * (st << 1)) + (t % st);
                int j = i + st;
                float vi = sv[i], vj = sv[j];
                int ii = si[i], ij = si[j];
                bool descend = ((i & sz) == 0);
                bool igreater = (vi > vj) || (vi == vj && ii < ij);
                if (igreater != descend) {
                    sv[i] = vj; sv[j] = vi;
                    si[i] = ij; si[j] = ii;
                }
            }
            __syncthreads();
        }
    }
    for (int j = tid; j < k; j += blockDim.x) idx_out[b * k + j] = si[j];
}

// ---------------- induced subgraph gather + degree ----------------
// wave per (b,i): Aout[b,i,j] = Ain[b, idx_i, idx_j]; dinv_out = rsqrt(rowsum)
__global__ __launch_bounds__(256) void gatherA_kernel(
    const float* __restrict__ Ain, const int* __restrict__ idx,
    float* __restrict__ Aout, float* __restrict__ dinv_out, int n, int k)
{
    int wid = (blockIdx.x * blockDim.x + threadIdx.x) >> 6;
    int lane = threadIdx.x & 63;
    int b = wid / k, i = wid % k;
    int isrc = idx[b * k + i];
    const float* src = Ain + ((size_t)b * n + isrc) * n;
    float s = 0.f;
    for (int c = lane; c < k; c += 64) {
        int jsrc = idx[b * k + c];
        float v = src[jsrc];
        Aout[((size_t)b * k + i) * k + c] = v;
        s += v;
    }
    s = wsum(s);
    if (lane == 0) dinv_out[b * k + i] = rsqrtf(s);
}

// ---------------- node feature gather with score gating ----------------
__global__ __launch_bounds__(256) void gatherX_kernel(
    const float* __restrict__ G, const float* __restrict__ score,
    const int* __restrict__ idx, float* __restrict__ Xout, int n, int k)
{
    int wid = (blockIdx.x * blockDim.x + threadIdx.x) >> 6;
    int lane = threadIdx.x & 63;
    int b = wid / k, i = wid % k;
    int isrc = idx[b * k + i];
    float sc = score[b * n + isrc];
    const float* g = G + ((size_t)b * n + isrc) * HH;
    float* xo = Xout + ((size_t)b * k + i) * HH;
    xo[lane] = g[lane] * sc;
    xo[lane + 64] = g[lane + 64] * sc;
}

// ---------------- readout (mean & max over nodes), accumulate ----------------
__global__ void readout_kernel(const float* __restrict__ X, float* __restrict__ R,
                               int k, int first)
{
    int b = blockIdx.x, h = threadIdx.x;  // 128 threads
    float s = 0.f, m = -INFINITY;
    for (int i = 0; i < k; ++i) {
        float v = X[((size_t)b * k + i) * HH + h];
        s += v;
        m = fmaxf(m, v);
    }
    float mean = s / (float)k;
    if (first) {
        R[b * 256 + h] = mean;
        R[b * 256 + 128 + h] = m;
    } else {
        R[b * 256 + h] += mean;
        R[b * 256 + 128 + h] += m;
    }
}

// ---------------- ||p|| for the 3 pooling vectors ----------------
__global__ void pnorm_kernel(const float* p1, const float* p2, const float* p3,
                             float* __restrict__ pnorm)
{
    int w = threadIdx.x >> 6, lane = threadIdx.x & 63;
    if (w < 3) {
        const float* p = (w == 0) ? p1 : (w == 1) ? p2 : p3;
        float v0 = p[lane], v1 = p[lane + 64];
        float s = wsum(v0 * v0 + v1 * v1);
        if (lane == 0) pnorm[w] = sqrtf(s);
    }
}

// ---------------- pack 4 conv weights into one [1024,768] matrix ----------------
// column layout: base(br) + j*32 + co ; bases {0,96,256,480}, k {3,5,7,9}
__global__ void pack_wcat(const float* __restrict__ cw0, const float* __restrict__ cw1,
                          const float* __restrict__ cw2, const float* __restrict__ cw3,
                          float* __restrict__ Wcat)
{
    int t = blockIdx.x * blockDim.x + threadIdx.x;
    if (t >= FINN * 768) return;
    int col = t % 768, ci = t / 768;
    const float* cw;
    int k, base;
    if (col < 96)       { cw = cw0; k = 3; base = 0; }
    else if (col < 256) { cw = cw1; k = 5; base = 96; }
    else if (col < 480) { cw = cw2; k = 7; base = 256; }
    else                { cw = cw3; k = 9; base = 480; }
    int rel = col - base;
    int j = rel >> 5, co = rel & 31;
    Wcat[t] = cw[(size_t)co * FINN * k + (size_t)ci * k + j];
}

// ---------------- conv shifted-sum + bias + relu + global max over time --------
__global__ __launch_bounds__(256) void conv_reduce(
    const float* __restrict__ P,
    const float* __restrict__ cb0, const float* __restrict__ cb1,
    const float* __restrict__ cb2, const float* __restrict__ cb3,
    float* __restrict__ seq)
{
    int b = blockIdx.x >> 2, br = blockIdx.x & 3;
    int k = 3 + 2 * br;
    int base = (br == 0) ? 0 : (br == 1) ? 96 : (br == 2) ? 256 : 480;
    int T = LL - k + 1;
    int co = threadIdx.x & 31, ts = threadIdx.x >> 5;  // 8 time-slots
    const float* cb = (br == 0) ? cb0 : (br == 1) ? cb1 : (br == 2) ? cb2 : cb3;
    float bias = cb[co];
    float m = -INFINITY;
    for (int t = ts; t < T; t += 8) {
        float acc = 0.f;
        for (int j = 0; j < k; ++j)
            acc += P[((size_t)b * LL + t + j) * 768 + base + j * 32 + co];
        m = fmaxf(m, acc + bias);
    }
    __shared__ float red[256];
    red[threadIdx.x] = m;
    __syncthreads();
    if (threadIdx.x < 32) {
        for (int s = 1; s < 8; ++s) m = fmaxf(m, red[co + s * 32]);
        seq[b * 128 + br * 32 + co] = fmaxf(m, 0.f);
    }
}

// ---------------- gated fusion ----------------
__global__ void gate_kernel(const float* __restrict__ gnn, const float* __restrict__ seq1,
                            const float* __restrict__ gate, float* __restrict__ gc0)
{
    int t = blockIdx.x * blockDim.x + threadIdx.x;
    if (t < B64 * HH) {
        float w = 1.f / (1.f + expf(-gate[0]));
        gc0[t] = (1.f - w) * gnn[t] + w * seq1[t];
    }
}

// ---------------- final 256->2 layer + relu + softmax ----------------
__global__ void head_kernel(const float* __restrict__ gc2, const float* __restrict__ out_w,
                            const float* __restrict__ out_b, float* __restrict__ out)
{
    int b = blockIdx.x, lane = threadIdx.x;  // 64 threads = 1 wave
    float a0 = 0.f, a1 = 0.f;
    for (int q = lane; q < 256; q += 64) {
        float v = gc2[b * 256 + q];
        a0 = fmaf(v, out_w[q * 2 + 0], a0);
        a1 = fmaf(v, out_w[q * 2 + 1], a1);
    }
    a0 = wsum(a0);
    a1 = wsum(a1);
    if (lane == 0) {
        float l0 = fmaxf(a0 + out_b[0], 0.f);
        float l1 = fmaxf(a1 + out_b[1], 0.f);
        float mm = fmaxf(l0, l1);
        float e0 = expf(l0 - mm), e1 = expf(l1 - mm);
        float d = e0 + e1;
        out[b * 2 + 0] = e0 / d;
        out[b * 2 + 1] = e1 / d;
    }
}

// =======================================================================
extern "C" void kernel_launch(void* const* d_in, const int* in_sizes, int n_in,
                              void* d_out, int out_size, void* d_ws, size_t ws_size,
                              hipStream_t stream)
{
    const float* adj      = (const float*)d_in[0];
    const float* feat     = (const float*)d_in[1];
    const float* pad_dmap = (const float*)d_in[2];
    const float* W1 = (const float*)d_in[3];
    const float* b1 = (const float*)d_in[4];
    const float* p1 = (const float*)d_in[5];
    const float* W2 = (const float*)d_in[6];
    const float* b2 = (const float*)d_in[7];
    const float* p2 = (const float*)d_in[8];
    const float* W3 = (const float*)d_in[9];
    const float* b3 = (const float*)d_in[10];
    const float* p3 = (const float*)d_in[11];
    const float* cat_w = (const float*)d_in[12];
    const float* cat_b = (const float*)d_in[13];
    const float* cw0 = (const float*)d_in[14];
    const float* cb0 = (const float*)d_in[15];
    const float* cw1 = (const float*)d_in[16];
    const float* cb1 = (const float*)d_in[17];
    const float* cw2 = (const float*)d_in[18];
    const float* cb2 = (const float*)d_in[19];
    const float* cw3 = (const float*)d_in[20];
    const float* cb3 = (const float*)d_in[21];
    const float* tf_w = (const float*)d_in[22];
    const float* tf_b = (const float*)d_in[23];
    const float* w1_gate = (const float*)d_in[24];
    const float* fc1_w = (const float*)d_in[25];
    const float* fc1_b = (const float*)d_in[26];
    const float* fc2_w = (const float*)d_in[27];
    const float* fc2_b = (const float*)d_in[28];
    const float* out_w = (const float*)d_in[29];
    const float* out_b = (const float*)d_in[30];
    float* out = (float*)d_out;

    char* ws = (char*)d_ws;
    auto al = [](size_t x) { return (x + 255) & ~(size_t)255; };
    size_t off = 0;
    auto alloc = [&](size_t nbytes) { size_t o = off; off += al(nbytes); return o; };

    // persistent small buffers
    float* pnorm  = (float*)(ws + alloc(3 * 4));
    float* dinv1  = (float*)(ws + alloc((size_t)B64 * NN * 4));
    float* score1 = (float*)(ws + alloc((size_t)B64 * NN * 4));
    int*   idx1   = (int*)  (ws + alloc((size_t)B64 * KK1 * 4));
    float* dinv2  = (float*)(ws + alloc((size_t)B64 * KK1 * 4));
    float* score2 = (float*)(ws + alloc((size_t)B64 * KK1 * 4));
    int*   idx2   = (int*)  (ws + alloc((size_t)B64 * KK2 * 4));
    float* dinv3  = (float*)(ws + alloc((size_t)B64 * KK2 * 4));
    float* score3 = (float*)(ws + alloc((size_t)B64 * KK2 * 4));
    int*   idx3   = (int*)  (ws + alloc((size_t)B64 * KK3 * 4));
    float* R      = (float*)(ws + alloc((size_t)B64 * 256 * 4));
    float* seq    = (float*)(ws + alloc((size_t)B64 * 128 * 4));
    float* seq1   = (float*)(ws + alloc((size_t)B64 * 128 * 4));
    float* gnn    = (float*)(ws + alloc((size_t)B64 * 128 * 4));
    float* gc0    = (float*)(ws + alloc((size_t)B64 * 128 * 4));
    float* gc1    = (float*)(ws + alloc((size_t)B64 * 512 * 4));
    float* gc2    = (float*)(ws + alloc((size_t)B64 * 256 * 4));

    // big region: CNN phase buffers alias GNN phase buffers (CNN completes first)
    size_t big = off;
    // CNN phase
    float* Wcat = (float*)(ws + big);
    size_t cnnoff = big + al((size_t)FINN * 768 * 4);
    float* P = (float*)(ws + cnnoff);
    size_t cnn_end = cnnoff + al((size_t)B64 * LL * 768 * 4);
    // GNN phase (aliased)
    size_t g = big;
    float* HT = (float*)(ws + g); g += al((size_t)B64 * NN * HH * 4);
    float* G  = (float*)(ws + g); g += al((size_t)B64 * NN * HH * 4);
    float* A1 = (float*)(ws + g); g += al((size_t)B64 * KK1 * KK1 * 4);
    float* X1 = (float*)(ws + g); g += al((size_t)B64 * KK1 * HH * 4);
    float* A2 = (float*)(ws + g); g += al((size_t)B64 * KK2 * KK2 * 4);
    float* X2 = (float*)(ws + g); g += al((size_t)B64 * KK2 * HH * 4);
    float* X3 = (float*)(ws + g); g += al((size_t)B64 * KK3 * HH * 4);
    size_t gnn_end = g;
    size_t need = (cnn_end > gnn_end) ? cnn_end : gnn_end;
    if (ws_size < need) return;  // workspace too small -> will show as validation failure

    // ---------------- CNN phase ----------------
    pack_wcat<<<(FINN * 768 + 255) / 256, 256, 0, stream>>>(cw0, cw1, cw2, cw3, Wcat);
    {   // P = pad_dmap[32768,1024] @ Wcat[1024,768]
        dim3 grid(768 / 128, (B64 * LL) / 128);
        sgemm_k<8><<<grid, 256, 0, stream>>>(pad_dmap, Wcat, P, B64 * LL, 768, FINN,
                                             nullptr, nullptr, 0);
    }
    conv_reduce<<<B64 * 4, 256, 0, stream>>>(P, cb0, cb1, cb2, cb3, seq);
    {   // seq1 = relu(seq @ tf_w + tf_b)
        dim3 grid(1, 1);
        sgemm_k<4><<<grid, 256, 0, stream>>>(seq, tf_w, seq1, B64, 128, 128,
                                             nullptr, tf_b, 1);
    }

    // ---------------- GNN phase ----------------
    pnorm_kernel<<<1, 256, 0, stream>>>(p1, p2, p3, pnorm);
    rowsum_kernel<<<(B64 * NN) / 4, 256, 0, stream>>>(adj, dinv1, NN);
    {   // h1 = (feat @ W1) * dinv1
        dim3 grid(1, (B64 * NN) / 64);
        sgemm_k<4><<<grid, 256, 0, stream>>>(feat, W1, HT, B64 * NN, HH, FINN,
                                             dinv1, nullptr, 0);
    }
    spmm_gcn<<<(B64 * NN) / 4, 256, 0, stream>>>(adj, HT, dinv1, b1, p1, pnorm + 0,
                                                 G, score1, NN);
    topk_kernel<<<B64, 256, 0, stream>>>(score1, idx1, NN, KK1);
    gatherA_kernel<<<(B64 * KK1) / 4, 256, 0, stream>>>(adj, idx1, A1, dinv2, NN, KK1);
    gatherX_kernel<<<(B64 * KK1) / 4, 256, 0, stream>>>(G, score1, idx1, X1, NN, KK1);
    readout_kernel<<<B64, 128, 0, stream>>>(X1, R, KK1, 1);

    {   // h2 = (x1 @ W2) * dinv2
        dim3 grid(1, (B64 * KK1) / 64);
        sgemm_k<4><<<grid, 256, 0, stream>>>(X1, W2, HT, B64 * KK1, HH, HH,
                                             dinv2, nullptr, 0);
    }
    spmm_gcn<<<(B64 * KK1) / 4, 256, 0, stream>>>(A1, HT, dinv2, b2, p2, pnorm + 1,
                                                  G, score2, KK1);
    topk_kernel<<<B64, 256, 0, stream>>>(score2, idx2, KK1, KK2);
    gatherA_kernel<<<(B64 * KK2) / 4, 256, 0, stream>>>(A1, idx2, A2, dinv3, KK1, KK2);
    gatherX_kernel<<<(B64 * KK2) / 4, 256, 0, stream>>>(G, score2, idx2, X2, KK1, KK2);
    readout_kernel<<<B64, 128, 0, stream>>>(X2, R, KK2, 0);

    {   // h3 = (x2 @ W3) * dinv3
        dim3 grid(1, (B64 * KK2) / 64);
        sgemm_k<4><<<grid, 256, 0, stream>>>(X2, W3, HT, B64 * KK2, HH, HH,
                                             dinv3, nullptr, 0);
    }
    spmm_gcn<<<(B64 * KK2) / 4, 256, 0, stream>>>(A2, HT, dinv3, b3, p3, pnorm + 2,
                                                  G, score3, KK2);
    topk_kernel<<<B64, 256, 0, stream>>>(score3, idx3, KK2, KK3);
    gatherX_kernel<<<(B64 * KK3) / 4, 256, 0, stream>>>(G, score3, idx3, X3, KK2, KK3);
    readout_kernel<<<B64, 128, 0, stream>>>(X3, R, KK3, 0);

    {   // gnn = relu(R @ cat_w + cat_b)
        dim3 grid(1, 1);
        sgemm_k<4><<<grid, 256, 0, stream>>>(R, cat_w, gnn, B64, 128, 256,
                                             nullptr, cat_b, 1);
    }

    // ---------------- fusion + head ----------------
    gate_kernel<<<(B64 * HH + 255) / 256, 256, 0, stream>>>(gnn, seq1, w1_gate, gc0);
    {   // gc1 = relu(gc0 @ fc1_w + fc1_b)
        dim3 grid(512 / 128, 1);
        sgemm_k<4><<<grid, 256, 0, stream>>>(gc0, fc1_w, gc1, B64, 512, 128,
                                             nullptr, fc1_b, 1);
    }
    {   // gc2 = relu(gc1 @ fc2_w + fc2_b)
        dim3 grid(256 / 128, 1);
        sgemm_k<4><<<grid, 256, 0, stream>>>(gc1, fc2_w, gc2, B64, 256, 512,
                                             nullptr, fc2_b, 1);
    }
    head_kernel<<<B64, 64, 0, stream>>>(gc2, out_w, out_b, out);
}

// Round 2
// 1117.244 us; speedup vs baseline: 1.3807x; 1.3807x over previous
//
#include <hip/hip_runtime.h>
#include <math.h>

// Problem constants (from reference)
#define B64  64
#define NN   512
#define FINN 1024
#define HH   128
#define LL   512
#define KK1  256
#define KK2  128
#define KK3  64

typedef __attribute__((ext_vector_type(8))) short short8v;
typedef __attribute__((ext_vector_type(4))) float f32x4;

// ---------------- helpers ----------------
__device__ __forceinline__ float wsum(float v) {
#pragma unroll
    for (int off = 32; off; off >>= 1) v += __shfl_xor(v, off, 64);
    return v;
}

__device__ __forceinline__ short f2bf(float x) {
    union { float f; unsigned u; } v; v.f = x;
    unsigned r = v.u + 0x7fffu + ((v.u >> 16) & 1u);  // RNE
    return (short)(r >> 16);
}

// ---------------- bf16 MFMA GEMM for the CNN branch ----------------
// C[M,N] = A_f32[M,K] @ B  where B is given as BT_bf16[N,K] (transposed).
// 128x128 tile, BK=32 (one full MFMA K-depth), 4 waves, reg-staged with
// fused fp32->bf16 conversion of A. LDS rows padded to 40 bf16 (80B) for
// 16B-aligned ds_read_b128 with <=2-way bank aliasing.
#define LDAP 40
__global__ __launch_bounds__(256) void mfma_cnn_gemm(
    const float* __restrict__ A, const short* __restrict__ BT,
    float* __restrict__ C, int M, int N, int K)
{
    __shared__ short As[128 * LDAP];
    __shared__ short Bs[128 * LDAP];
    const int tid = threadIdx.x;
    const int lane = tid & 63;
    const int wid = tid >> 6;
    const int m0 = blockIdx.y * 128;
    const int n0 = blockIdx.x * 128;
    const int wr = (wid >> 1) * 64;   // wave row offset in tile
    const int wc = (wid & 1) * 64;    // wave col offset in tile

    f32x4 acc[4][4];
#pragma unroll
    for (int i = 0; i < 4; ++i)
#pragma unroll
        for (int j = 0; j < 4; ++j) acc[i][j] = (f32x4){0.f, 0.f, 0.f, 0.f};

    // staging coordinates: 2 threads per row, 16 k each
    const int srow = tid >> 1;
    const int skq = (tid & 1) * 16;
    const float* Aptr = A + (size_t)(m0 + srow) * K + skq;
    const short* Bptr = BT + (size_t)(n0 + srow) * K + skq;

    const int fr = lane & 15;          // M/N index within 16-fragment
    const int fk = (lane >> 4) * 8;    // k offset within fragment
    const int crow = (lane >> 4) * 4;  // C-row base within fragment

    for (int k0 = 0; k0 < K; k0 += 32) {
        // ---- stage A (fp32 -> bf16) ----
        float4 fa0 = *(const float4*)(Aptr + k0);
        float4 fa1 = *(const float4*)(Aptr + k0 + 4);
        float4 fa2 = *(const float4*)(Aptr + k0 + 8);
        float4 fa3 = *(const float4*)(Aptr + k0 + 12);
        // ---- stage B (already bf16): 32 bytes ----
        float4 fb0 = *(const float4*)(Bptr + k0);      // 8 bf16
        float4 fb1 = *(const float4*)(Bptr + k0 + 8);  // 8 bf16
        __syncthreads();  // previous compute done before overwrite
        short8v ha, hb;
        ha[0] = f2bf(fa0.x); ha[1] = f2bf(fa0.y); ha[2] = f2bf(fa0.z); ha[3] = f2bf(fa0.w);
        ha[4] = f2bf(fa1.x); ha[5] = f2bf(fa1.y); ha[6] = f2bf(fa1.z); ha[7] = f2bf(fa1.w);
        hb[0] = f2bf(fa2.x); hb[1] = f2bf(fa2.y); hb[2] = f2bf(fa2.z); hb[3] = f2bf(fa2.w);
        hb[4] = f2bf(fa3.x); hb[5] = f2bf(fa3.y); hb[6] = f2bf(fa3.z); hb[7] = f2bf(fa3.w);
        *(short8v*)&As[srow * LDAP + skq] = ha;
        *(short8v*)&As[srow * LDAP + skq + 8] = hb;
        *(short8v*)&Bs[srow * LDAP + skq] = *(const short8v*)&fb0;
        *(short8v*)&Bs[srow * LDAP + skq + 8] = *(const short8v*)&fb1;
        __syncthreads();

        // ---- fragments + MFMA ----
        short8v af[4], bfr[4];
#pragma unroll
        for (int i = 0; i < 4; ++i) {
            af[i] = *(const short8v*)&As[(wr + i * 16 + fr) * LDAP + fk];
            bfr[i] = *(const short8v*)&Bs[(wc + i * 16 + fr) * LDAP + fk];
        }
#pragma unroll
        for (int mi = 0; mi < 4; ++mi)
#pragma unroll
            for (int ni = 0; ni < 4; ++ni)
                acc[mi][ni] = __builtin_amdgcn_mfma_f32_16x16x32_bf16(
                    af[mi], bfr[ni], acc[mi][ni], 0, 0, 0);
    }

    // ---- epilogue: C[row][col], row=(lane>>4)*4+r, col=lane&15 (verified m89/m91)
#pragma unroll
    for (int mi = 0; mi < 4; ++mi) {
#pragma unroll
        for (int ni = 0; ni < 4; ++ni) {
            int col = n0 + wc + ni * 16 + fr;
            size_t rbase = (size_t)(m0 + wr + mi * 16 + crow) * N + col;
#pragma unroll
            for (int r = 0; r < 4; ++r)
                C[rbase + (size_t)r * N] = acc[mi][ni][r];
        }
    }
}

// ---------------- generic fp32 GEMM (small layers) ----------------
template <int TM>
__global__ __launch_bounds__(256) void sgemm_k(
    const float* __restrict__ A, const float* __restrict__ Bm, float* __restrict__ C,
    int M, int N, int K,
    const float* __restrict__ rowscale, const float* __restrict__ bias, int do_relu)
{
    constexpr int BM = TM * 16;
    constexpr int BN = 128;
    constexpr int BK = 16;
    __shared__ float As[BK][BM + 4];
    __shared__ float Bs[BK][BN + 4];

    const int tid = threadIdx.x;
    const int tx = tid & 15;
    const int ty = tid >> 4;
    const int m0 = blockIdx.y * BM;
    const int n0 = blockIdx.x * BN;

    float acc[TM][8];
#pragma unroll
    for (int i = 0; i < TM; ++i)
#pragma unroll
        for (int j = 0; j < 8; ++j) acc[i][j] = 0.f;

    for (int k0 = 0; k0 < K; k0 += BK) {
#pragma unroll
        for (int i = 0; i < BM / 64; ++i) {
            int li = tid + 256 * i;
            int arow = li >> 2;
            int kq = (li & 3) << 2;
            float4 f = make_float4(0.f, 0.f, 0.f, 0.f);
            if (m0 + arow < M)
                f = *(const float4*)(A + (size_t)(m0 + arow) * K + k0 + kq);
            As[kq + 0][arow] = f.x;
            As[kq + 1][arow] = f.y;
            As[kq + 2][arow] = f.z;
            As[kq + 3][arow] = f.w;
        }
#pragma unroll
        for (int i = 0; i < 2; ++i) {
            int li = tid + 256 * i;
            int brow = li >> 5;
            int bcol = (li & 31) << 2;
            float4 f = *(const float4*)(Bm + (size_t)(k0 + brow) * N + n0 + bcol);
            *(float4*)&Bs[brow][bcol] = f;
        }
        __syncthreads();
#pragma unroll
        for (int kk = 0; kk < BK; ++kk) {
            float a[TM], bf[8];
            *(float4*)&a[0] = *(const float4*)&As[kk][ty * TM];
            if constexpr (TM == 8)
                *(float4*)&a[4] = *(const float4*)&As[kk][ty * TM + 4];
            *(float4*)&bf[0] = *(const float4*)&Bs[kk][tx * 8];
            *(float4*)&bf[4] = *(const float4*)&Bs[kk][tx * 8 + 4];
#pragma unroll
            for (int i = 0; i < TM; ++i)
#pragma unroll
                for (int j = 0; j < 8; ++j)
                    acc[i][j] = fmaf(a[i], bf[j], acc[i][j]);
        }
        __syncthreads();
    }

#pragma unroll
    for (int i = 0; i < TM; ++i) {
        int r = m0 + ty * TM + i;
        if (r >= M) continue;
        float scale = rowscale ? rowscale[r] : 1.f;
        float out[8];
#pragma unroll
        for (int j = 0; j < 8; ++j) {
            float v = acc[i][j] * scale;
            if (bias) v += bias[n0 + tx * 8 + j];
            if (do_relu) v = fmaxf(v, 0.f);
            out[j] = v;
        }
        float* cp = C + (size_t)r * N + n0 + tx * 8;
        *(float4*)&cp[0] = *(float4*)&out[0];
        *(float4*)&cp[4] = *(float4*)&out[4];
    }
}

// ---------------- adjacency row-sum -> rsqrt(deg) ----------------
__global__ __launch_bounds__(256) void rowsum_kernel(
    const float* __restrict__ A, float* __restrict__ dinv, int n)
{
    int wid = (blockIdx.x * blockDim.x + threadIdx.x) >> 6;
    int lane = threadIdx.x & 63;
    const float* Arow = A + (size_t)wid * n;
    float s = 0.f;
    for (int c = lane; c < n; c += 64) s += Arow[c];
    s = wsum(s);
    if (lane == 0) dinv[wid] = (s > 0.f) ? rsqrtf(s) : 0.f;
}

// ---------------- SpMM + GCN epilogue + fused score ----------------
__global__ __launch_bounds__(256) void spmm_gcn(
    const float* __restrict__ A, const float* __restrict__ Hin,
    const float* __restrict__ dinv, const float* __restrict__ bias,
    const float* __restrict__ p, const float* __restrict__ pnorm,
    float* __restrict__ Gout, float* __restrict__ score, int n)
{
    int wid = (blockIdx.x * blockDim.x + threadIdx.x) >> 6;
    int lane = threadIdx.x & 63;
    int b = wid / n, row = wid % n;
    const float* Arow = A + ((size_t)b * n + row) * n;
    float acc0 = 0.f, acc1 = 0.f;
    for (int c = 0; c < n; c += 64) {
        float av = Arow[c + lane];
        unsigned long long mask = __ballot(av != 0.0f);
        while (mask) {
            int i = __ffsll((unsigned long long)mask) - 1;
            mask &= mask - 1;
            float val = __shfl(av, i, 64);
            const float* hr = Hin + ((size_t)b * n + c + i) * HH;
            acc0 = fmaf(val, hr[lane], acc0);
            acc1 = fmaf(val, hr[lane + 64], acc1);
        }
    }
    float dv = dinv[b * n + row];
    float g0 = fmaxf(fmaf(acc0, dv, bias[lane]), 0.f);
    float g1 = fmaxf(fmaf(acc1, dv, bias[lane + 64]), 0.f);
    float* gr = Gout + ((size_t)b * n + row) * HH;
    gr[lane] = g0;
    gr[lane + 64] = g1;
    float s = g0 * p[lane] + g1 * p[lane + 64];
    s = wsum(s);
    if (lane == 0) score[b * n + row] = tanhf(s / (pnorm[0] + 1e-12f));
}

// ---------------- per-batch top-k (bitonic, stable ties) ----------------
__global__ __launch_bounds__(256) void topk_kernel(
    const float* __restrict__ score, int* __restrict__ idx_out, int n, int k)
{
    __shared__ float sv[512];
    __shared__ int si[512];
    int b = blockIdx.x, tid = threadIdx.x;
    for (int j = tid; j < n; j += blockDim.x) { sv[j] = score[b * n + j]; si[j] = j; }
    __syncthreads();
    for (int sz = 2; sz <= n; sz <<= 1) {
        for (int st = sz >> 1; st; st >>= 1) {
            for (int t = tid; t < (n >> 1); t += blockDim.x) {
                int i = ((t / st) * (st << 1)) + (t % st);
                int j = i + st;
                float vi = sv[i], vj = sv[j];
                int ii = si[i], ij = si[j];
                bool descend = ((i & sz) == 0);
                bool igreater = (vi > vj) || (vi == vj && ii < ij);
                if (igreater != descend) {
                    sv[i] = vj; sv[j] = vi;
                    si[i] = ij; si[j] = ii;
                }
            }
            __syncthreads();
        }
    }
    for (int j = tid; j < k; j += blockDim.x) idx_out[b * k + j] = si[j];
}

// ---------------- induced subgraph gather + degree ----------------
__global__ __launch_bounds__(256) void gatherA_kernel(
    const float* __restrict__ Ain, const int* __restrict__ idx,
    float* __restrict__ Aout, float* __restrict__ dinv_out, int n, int k)
{
    int wid = (blockIdx.x * blockDim.x + threadIdx.x) >> 6;
    int lane = threadIdx.x & 63;
    int b = wid / k, i = wid % k;
    int isrc = idx[b * k + i];
    const float* src = Ain + ((size_t)b * n + isrc) * n;
    float s = 0.f;
    for (int c = lane; c < k; c += 64) {
        int jsrc = idx[b * k + c];
        float v = src[jsrc];
        Aout[((size_t)b * k + i) * k + c] = v;
        s += v;
    }
    s = wsum(s);
    if (lane == 0) dinv_out[b * k + i] = rsqrtf(s);
}

// ---------------- node feature gather with score gating ----------------
__global__ __launch_bounds__(256) void gatherX_kernel(
    const float* __restrict__ G, const float* __restrict__ score,
    const int* __restrict__ idx, float* __restrict__ Xout, int n, int k)
{
    int wid = (blockIdx.x * blockDim.x + threadIdx.x) >> 6;
    int lane = threadIdx.x & 63;
    int b = wid / k, i = wid % k;
    int isrc = idx[b * k + i];
    float sc = score[b * n + isrc];
    const float* g = G + ((size_t)b * n + isrc) * HH;
    float* xo = Xout + ((size_t)b * k + i) * HH;
    xo[lane] = g[lane] * sc;
    xo[lane + 64] = g[lane + 64] * sc;
}

// ---------------- readout (mean & max over nodes), accumulate ----------------
__global__ void readout_kernel(const float* __restrict__ X, float* __restrict__ R,
                               int k, int first)
{
    int b = blockIdx.x, h = threadIdx.x;  // 128 threads
    float s = 0.f, m = -INFINITY;
    for (int i = 0; i < k; ++i) {
        float v = X[((size_t)b * k + i) * HH + h];
        s += v;
        m = fmaxf(m, v);
    }
    float mean = s / (float)k;
    if (first) {
        R[b * 256 + h] = mean;
        R[b * 256 + 128 + h] = m;
    } else {
        R[b * 256 + h] += mean;
        R[b * 256 + 128 + h] += m;
    }
}

// ---------------- ||p|| for the 3 pooling vectors ----------------
__global__ void pnorm_kernel(const float* p1, const float* p2, const float* p3,
                             float* __restrict__ pnorm)
{
    int w = threadIdx.x >> 6, lane = threadIdx.x & 63;
    if (w < 3) {
        const float* p = (w == 0) ? p1 : (w == 1) ? p2 : p3;
        float v0 = p[lane], v1 = p[lane + 64];
        float s = wsum(v0 * v0 + v1 * v1);
        if (lane == 0) pnorm[w] = sqrtf(s);
    }
}

// ---------------- pack 4 conv weights -> WcatT bf16 [768][1024] ----------------
// column layout: base(br) + j*32 + co ; bases {0,96,256,480}, k {3,5,7,9}
__global__ void pack_wcatT(const float* __restrict__ cw0, const float* __restrict__ cw1,
                           const float* __restrict__ cw2, const float* __restrict__ cw3,
                           short* __restrict__ WT)
{
    int e = blockIdx.x * blockDim.x + threadIdx.x;
    if (e >= 768 * FINN) return;
    int ci = e & (FINN - 1);
    int col = e >> 10;
    const float* cw;
    int k, base;
    if (col < 96)       { cw = cw0; k = 3; base = 0; }
    else if (col < 256) { cw = cw1; k = 5; base = 96; }
    else if (col < 480) { cw = cw2; k = 7; base = 256; }
    else                { cw = cw3; k = 9; base = 480; }
    int rel = col - base;
    int j = rel >> 5, co = rel & 31;
    WT[e] = f2bf(cw[((size_t)co * FINN + ci) * k + j]);
}

// ---------------- conv shifted-sum + bias + relu + global max over time --------
__global__ __launch_bounds__(256) void conv_reduce(
    const float* __restrict__ P,
    const float* __restrict__ cb0, const float* __restrict__ cb1,
    const float* __restrict__ cb2, const float* __restrict__ cb3,
    float* __restrict__ seq)
{
    int b = blockIdx.x >> 2, br = blockIdx.x & 3;
    int k = 3 + 2 * br;
    int base = (br == 0) ? 0 : (br == 1) ? 96 : (br == 2) ? 256 : 480;
    int T = LL - k + 1;
    int co = threadIdx.x & 31, ts = threadIdx.x >> 5;
    const float* cb = (br == 0) ? cb0 : (br == 1) ? cb1 : (br == 2) ? cb2 : cb3;
    float bias = cb[co];
    float m = -INFINITY;
    for (int t = ts; t < T; t += 8) {
        float acc = 0.f;
        for (int j = 0; j < k; ++j)
            acc += P[((size_t)b * LL + t + j) * 768 + base + j * 32 + co];
        m = fmaxf(m, acc + bias);
    }
    __shared__ float red[256];
    red[threadIdx.x] = m;
    __syncthreads();
    if (threadIdx.x < 32) {
        for (int s = 1; s < 8; ++s) m = fmaxf(m, red[co + s * 32]);
        seq[b * 128 + br * 32 + co] = fmaxf(m, 0.f);
    }
}

// ---------------- gated fusion ----------------
__global__ void gate_kernel(const float* __restrict__ gnn, const float* __restrict__ seq1,
                            const float* __restrict__ gate, float* __restrict__ gc0)
{
    int t = blockIdx.x * blockDim.x + threadIdx.x;
    if (t < B64 * HH) {
        float w = 1.f / (1.f + expf(-gate[0]));
        gc0[t] = (1.f - w) * gnn[t] + w * seq1[t];
    }
}

// ---------------- final 256->2 layer + relu + softmax ----------------
__global__ void head_kernel(const float* __restrict__ gc2, const float* __restrict__ out_w,
                            const float* __restrict__ out_b, float* __restrict__ out)
{
    int b = blockIdx.x, lane = threadIdx.x;
    float a0 = 0.f, a1 = 0.f;
    for (int q = lane; q < 256; q += 64) {
        float v = gc2[b * 256 + q];
        a0 = fmaf(v, out_w[q * 2 + 0], a0);
        a1 = fmaf(v, out_w[q * 2 + 1], a1);
    }
    a0 = wsum(a0);
    a1 = wsum(a1);
    if (lane == 0) {
        float l0 = fmaxf(a0 + out_b[0], 0.f);
        float l1 = fmaxf(a1 + out_b[1], 0.f);
        float mm = fmaxf(l0, l1);
        float e0 = expf(l0 - mm), e1 = expf(l1 - mm);
        float d = e0 + e1;
        out[b * 2 + 0] = e0 / d;
        out[b * 2 + 1] = e1 / d;
    }
}

// =======================================================================
extern "C" void kernel_launch(void* const* d_in, const int* in_sizes, int n_in,
                              void* d_out, int out_size, void* d_ws, size_t ws_size,
                              hipStream_t stream)
{
    const float* adj      = (const float*)d_in[0];
    const float* feat     = (const float*)d_in[1];
    const float* pad_dmap = (const float*)d_in[2];
    const float* W1 = (const float*)d_in[3];
    const float* b1 = (const float*)d_in[4];
    const float* p1 = (const float*)d_in[5];
    const float* W2 = (const float*)d_in[6];
    const float* b2 = (const float*)d_in[7];
    const float* p2 = (const float*)d_in[8];
    const float* W3 = (const float*)d_in[9];
    const float* b3 = (const float*)d_in[10];
    const float* p3 = (const float*)d_in[11];
    const float* cat_w = (const float*)d_in[12];
    const float* cat_b = (const float*)d_in[13];
    const float* cw0 = (const float*)d_in[14];
    const float* cb0 = (const float*)d_in[15];
    const float* cw1 = (const float*)d_in[16];
    const float* cb1 = (const float*)d_in[17];
    const float* cw2 = (const float*)d_in[18];
    const float* cb2 = (const float*)d_in[19];
    const float* cw3 = (const float*)d_in[20];
    const float* cb3 = (const float*)d_in[21];
    const float* tf_w = (const float*)d_in[22];
    const float* tf_b = (const float*)d_in[23];
    const float* w1_gate = (const float*)d_in[24];
    const float* fc1_w = (const float*)d_in[25];
    const float* fc1_b = (const float*)d_in[26];
    const float* fc2_w = (const float*)d_in[27];
    const float* fc2_b = (const float*)d_in[28];
    const float* out_w = (const float*)d_in[29];
    const float* out_b = (const float*)d_in[30];
    float* out = (float*)d_out;

    char* ws = (char*)d_ws;
    auto al = [](size_t x) { return (x + 255) & ~(size_t)255; };
    size_t off = 0;
    auto alloc = [&](size_t nbytes) { size_t o = off; off += al(nbytes); return o; };

    // persistent small buffers
    float* pnorm  = (float*)(ws + alloc(3 * 4));
    float* dinv1  = (float*)(ws + alloc((size_t)B64 * NN * 4));
    float* score1 = (float*)(ws + alloc((size_t)B64 * NN * 4));
    int*   idx1   = (int*)  (ws + alloc((size_t)B64 * KK1 * 4));
    float* dinv2  = (float*)(ws + alloc((size_t)B64 * KK1 * 4));
    float* score2 = (float*)(ws + alloc((size_t)B64 * KK1 * 4));
    int*   idx2   = (int*)  (ws + alloc((size_t)B64 * KK2 * 4));
    float* dinv3  = (float*)(ws + alloc((size_t)B64 * KK2 * 4));
    float* score3 = (float*)(ws + alloc((size_t)B64 * KK2 * 4));
    int*   idx3   = (int*)  (ws + alloc((size_t)B64 * KK3 * 4));
    float* R      = (float*)(ws + alloc((size_t)B64 * 256 * 4));
    float* seq    = (float*)(ws + alloc((size_t)B64 * 128 * 4));
    float* seq1   = (float*)(ws + alloc((size_t)B64 * 128 * 4));
    float* gnn    = (float*)(ws + alloc((size_t)B64 * 128 * 4));
    float* gc0    = (float*)(ws + alloc((size_t)B64 * 128 * 4));
    float* gc1    = (float*)(ws + alloc((size_t)B64 * 512 * 4));
    float* gc2    = (float*)(ws + alloc((size_t)B64 * 256 * 4));

    // big region: CNN phase buffers alias GNN phase buffers (CNN completes first)
    size_t big = off;
    // CNN phase
    short* WT = (short*)(ws + big);
    size_t cnnoff = big + al((size_t)768 * FINN * 2);
    float* P = (float*)(ws + cnnoff);
    size_t cnn_end = cnnoff + al((size_t)B64 * LL * 768 * 4);
    // GNN phase (aliased)
    size_t g = big;
    float* HT = (float*)(ws + g); g += al((size_t)B64 * NN * HH * 4);
    float* G  = (float*)(ws + g); g += al((size_t)B64 * NN * HH * 4);
    float* A1 = (float*)(ws + g); g += al((size_t)B64 * KK1 * KK1 * 4);
    float* X1 = (float*)(ws + g); g += al((size_t)B64 * KK1 * HH * 4);
    float* A2 = (float*)(ws + g); g += al((size_t)B64 * KK2 * KK2 * 4);
    float* X2 = (float*)(ws + g); g += al((size_t)B64 * KK2 * HH * 4);
    float* X3 = (float*)(ws + g); g += al((size_t)B64 * KK3 * HH * 4);
    size_t gnn_end = g;
    size_t need = (cnn_end > gnn_end) ? cnn_end : gnn_end;
    if (ws_size < need) return;

    // ---------------- CNN phase ----------------
    pack_wcatT<<<(768 * FINN + 255) / 256, 256, 0, stream>>>(cw0, cw1, cw2, cw3, WT);
    {   // P = pad_dmap[32768,1024] @ Wcat -> bf16 MFMA
        dim3 grid(768 / 128, (B64 * LL) / 128);
        mfma_cnn_gemm<<<grid, 256, 0, stream>>>(pad_dmap, WT, P, B64 * LL, 768, FINN);
    }
    conv_reduce<<<B64 * 4, 256, 0, stream>>>(P, cb0, cb1, cb2, cb3, seq);
    {   // seq1 = relu(seq @ tf_w + tf_b)
        dim3 grid(1, 1);
        sgemm_k<4><<<grid, 256, 0, stream>>>(seq, tf_w, seq1, B64, 128, 128,
                                             nullptr, tf_b, 1);
    }

    // ---------------- GNN phase ----------------
    pnorm_kernel<<<1, 256, 0, stream>>>(p1, p2, p3, pnorm);
    rowsum_kernel<<<(B64 * NN) / 4, 256, 0, stream>>>(adj, dinv1, NN);
    {   // h1 = (feat @ W1) * dinv1
        dim3 grid(1, (B64 * NN) / 64);
        sgemm_k<4><<<grid, 256, 0, stream>>>(feat, W1, HT, B64 * NN, HH, FINN,
                                             dinv1, nullptr, 0);
    }
    spmm_gcn<<<(B64 * NN) / 4, 256, 0, stream>>>(adj, HT, dinv1, b1, p1, pnorm + 0,
                                                 G, score1, NN);
    topk_kernel<<<B64, 256, 0, stream>>>(score1, idx1, NN, KK1);
    gatherA_kernel<<<(B64 * KK1) / 4, 256, 0, stream>>>(adj, idx1, A1, dinv2, NN, KK1);
    gatherX_kernel<<<(B64 * KK1) / 4, 256, 0, stream>>>(G, score1, idx1, X1, NN, KK1);
    readout_kernel<<<B64, 128, 0, stream>>>(X1, R, KK1, 1);

    {   // h2 = (x1 @ W2) * dinv2
        dim3 grid(1, (B64 * KK1) / 64);
        sgemm_k<4><<<grid, 256, 0, stream>>>(X1, W2, HT, B64 * KK1, HH, HH,
                                             dinv2, nullptr, 0);
    }
    spmm_gcn<<<(B64 * KK1) / 4, 256, 0, stream>>>(A1, HT, dinv2, b2, p2, pnorm + 1,
                                                  G, score2, KK1);
    topk_kernel<<<B64, 256, 0, stream>>>(score2, idx2, KK1, KK2);
    gatherA_kernel<<<(B64 * KK2) / 4, 256, 0, stream>>>(A1, idx2, A2, dinv3, KK1, KK2);
    gatherX_kernel<<<(B64 * KK2) / 4, 256, 0, stream>>>(G, score2, idx2, X2, KK1, KK2);
    readout_kernel<<<B64, 128, 0, stream>>>(X2, R, KK2, 0);

    {   // h3 = (x2 @ W3) * dinv3
        dim3 grid(1, (B64 * KK2) / 64);
        sgemm_k<4><<<grid, 256, 0, stream>>>(X2, W3, HT, B64 * KK2, HH, HH,
                                             dinv3, nullptr, 0);
    }
    spmm_gcn<<<(B64 * KK2) / 4, 256, 0, stream>>>(A2, HT, dinv3, b3, p3, pnorm + 2,
                                                  G, score3, KK2);
    topk_kernel<<<B64, 256, 0, stream>>>(score3, idx3, KK2, KK3);
    gatherX_kernel<<<(B64 * KK3) / 4, 256, 0, stream>>>(G, score3, idx3, X3, KK2, KK3);
    readout_kernel<<<B64, 128, 0, stream>>>(X3, R, KK3, 0);

    {   // gnn = relu(R @ cat_w + cat_b)
        dim3 grid(1, 1);
        sgemm_k<4><<<grid, 256, 0, stream>>>(R, cat_w, gnn, B64, 128, 256,
                                             nullptr, cat_b, 1);
    }

    // ---------------- fusion + head ----------------
    gate_kernel<<<(B64 * HH + 255) / 256, 256, 0, stream>>>(gnn, seq1, w1_gate, gc0);
    {   // gc1 = relu(gc0 @ fc1_w + fc1_b)
        dim3 grid(512 / 128, 1);
        sgemm_k<4><<<grid, 256, 0, stream>>>(gc0, fc1_w, gc1, B64, 512, 128,
                                             nullptr, fc1_b, 1);
    }
    {   // gc2 = relu(gc1 @ fc2_w + fc2_b)
        dim3 grid(256 / 128, 1);
        sgemm_k<4><<<grid, 256, 0, stream>>>(gc1, fc2_w, gc2, B64, 256, 512,
                                             nullptr, fc2_b, 1);
    }
    head_kernel<<<B64, 64, 0, stream>>>(gc2, out_w, out_b, out);
}

// Round 4
// 802.830 us; speedup vs baseline: 1.9214x; 1.3916x over previous
//
#include <hip/hip_runtime.h>
#include <math.h>

// Problem constants (from reference)
#define B64  64
#define NN   512
#define FINN 1024
#define HH   128
#define LL   512
#define KK1  256
#define KK2  128
#define KK3  64

typedef __attribute__((ext_vector_type(8))) short short8v;
typedef __attribute__((ext_vector_type(4))) short short4v;
typedef __attribute__((ext_vector_type(4))) float f32x4;

// ---------------- helpers ----------------
__device__ __forceinline__ float wsum(float v) {
#pragma unroll
    for (int off = 32; off; off >>= 1) v += __shfl_xor(v, off, 64);
    return v;
}

__device__ __forceinline__ short f2bf(float x) {
    union { float f; unsigned u; } v; v.f = x;
    unsigned r = v.u + 0x7fffu + ((v.u >> 16) & 1u);  // RNE
    return (short)(r >> 16);
}

// ---------------- bf16 MFMA GEMM ----------------
// C[M,N] = A_f32[M,K] @ B, B given as BT_bf16[N,K]. 128x128 tile, BK=32,
// 4 waves, reg-staged with fused fp32->bf16 convert of A. Optional per-row
// scale in epilogue. swz=1: XCD-chunked swizzle so blocks sharing an
// A-panel (consecutive work ids, ntx n-tiles) land on the same XCD's L2.
// Requires M%128==0, N%128==0, K%32==0.
#define LDAP 40
__global__ __launch_bounds__(256) void mfma_gemm(
    const float* __restrict__ A, const short* __restrict__ BT,
    float* __restrict__ C, int M, int N, int K,
    const float* __restrict__ rowscale, int ntx, int swz)
{
    __shared__ short As[128 * LDAP];
    __shared__ short Bs[128 * LDAP];
    int bid = blockIdx.x;
    if (swz) bid = (bid & 7) * (gridDim.x >> 3) + (bid >> 3);
    const int m0 = (bid / ntx) * 128;
    const int n0 = (bid % ntx) * 128;
    const int tid = threadIdx.x;
    const int lane = tid & 63;
    const int wid = tid >> 6;
    const int wr = (wid >> 1) * 64;
    const int wc = (wid & 1) * 64;

    f32x4 acc[4][4];
#pragma unroll
    for (int i = 0; i < 4; ++i)
#pragma unroll
        for (int j = 0; j < 4; ++j) acc[i][j] = (f32x4){0.f, 0.f, 0.f, 0.f};

    const int srow = tid >> 1;
    const int skq = (tid & 1) * 16;
    const float* Aptr = A + (size_t)(m0 + srow) * K + skq;
    const short* Bptr = BT + (size_t)(n0 + srow) * K + skq;

    const int fr = lane & 15;
    const int fk = (lane >> 4) * 8;
    const int crow = (lane >> 4) * 4;

    for (int k0 = 0; k0 < K; k0 += 32) {
        float4 fa0 = *(const float4*)(Aptr + k0);
        float4 fa1 = *(const float4*)(Aptr + k0 + 4);
        float4 fa2 = *(const float4*)(Aptr + k0 + 8);
        float4 fa3 = *(const float4*)(Aptr + k0 + 12);
        float4 fb0 = *(const float4*)(Bptr + k0);
        float4 fb1 = *(const float4*)(Bptr + k0 + 8);
        __syncthreads();
        short8v ha, hb;
        ha[0] = f2bf(fa0.x); ha[1] = f2bf(fa0.y); ha[2] = f2bf(fa0.z); ha[3] = f2bf(fa0.w);
        ha[4] = f2bf(fa1.x); ha[5] = f2bf(fa1.y); ha[6] = f2bf(fa1.z); ha[7] = f2bf(fa1.w);
        hb[0] = f2bf(fa2.x); hb[1] = f2bf(fa2.y); hb[2] = f2bf(fa2.z); hb[3] = f2bf(fa2.w);
        hb[4] = f2bf(fa3.x); hb[5] = f2bf(fa3.y); hb[6] = f2bf(fa3.z); hb[7] = f2bf(fa3.w);
        *(short8v*)&As[srow * LDAP + skq] = ha;
        *(short8v*)&As[srow * LDAP + skq + 8] = hb;
        *(short8v*)&Bs[srow * LDAP + skq] = *(const short8v*)&fb0;
        *(short8v*)&Bs[srow * LDAP + skq + 8] = *(const short8v*)&fb1;
        __syncthreads();

        short8v af[4], bfr[4];
#pragma unroll
        for (int i = 0; i < 4; ++i) {
            af[i] = *(const short8v*)&As[(wr + i * 16 + fr) * LDAP + fk];
            bfr[i] = *(const short8v*)&Bs[(wc + i * 16 + fr) * LDAP + fk];
        }
#pragma unroll
        for (int mi = 0; mi < 4; ++mi)
#pragma unroll
            for (int ni = 0; ni < 4; ++ni)
                acc[mi][ni] = __builtin_amdgcn_mfma_f32_16x16x32_bf16(
                    af[mi], bfr[ni], acc[mi][ni], 0, 0, 0);
    }

    // C/D layout: row=(lane>>4)*4+r, col=lane&15 (verified m89/m91)
#pragma unroll
    for (int mi = 0; mi < 4; ++mi) {
#pragma unroll
        for (int ni = 0; ni < 4; ++ni) {
            int col = n0 + wc + ni * 16 + fr;
#pragma unroll
            for (int r = 0; r < 4; ++r) {
                int row = m0 + wr + mi * 16 + crow + r;
                float v = acc[mi][ni][r];
                if (rowscale) v *= rowscale[row];
                C[(size_t)row * N + col] = v;
            }
        }
    }
}

// ---------------- prep: rowsum + weight packs + pnorm (one dispatch) ---------
// blocks [0,8192): rowsum(adj)->dinv1 ; [8192,8960): pack WT (CNN, bf16)
// [8960,9088): W1T ; [9088,9104): W2T ; [9104,9120): W3T ; [9120]: pnorm
__global__ __launch_bounds__(256) void prep_kernel(
    const float* __restrict__ adj, float* __restrict__ dinv,
    const float* __restrict__ cw0, const float* __restrict__ cw1,
    const float* __restrict__ cw2, const float* __restrict__ cw3,
    short* __restrict__ WT,
    const float* __restrict__ W1, short* __restrict__ W1T,
    const float* __restrict__ W2, short* __restrict__ W2T,
    const float* __restrict__ W3, short* __restrict__ W3T,
    const float* __restrict__ p1, const float* __restrict__ p2,
    const float* __restrict__ p3, float* __restrict__ pnorm)
{
    const int bid = blockIdx.x, tid = threadIdx.x;
    if (bid < 8192) {
        int wid = (bid * 256 + tid) >> 6;
        int lane = tid & 63;
        const float* Arow = adj + (size_t)wid * NN;
        float s = 0.f;
        for (int c = lane; c < NN; c += 64) s += Arow[c];
        s = wsum(s);
        if (lane == 0) dinv[wid] = (s > 0.f) ? rsqrtf(s) : 0.f;
    } else if (bid < 8960) {
        int e = (bid - 8192) * 1024 + tid * 4;
        int col = e >> 10, ci = e & 1023;
        const float* cw; int k, base;
        if (col < 96)       { cw = cw0; k = 3; base = 0; }
        else if (col < 256) { cw = cw1; k = 5; base = 96; }
        else if (col < 480) { cw = cw2; k = 7; base = 256; }
        else                { cw = cw3; k = 9; base = 480; }
        int rel = col - base;
        int j = rel >> 5, co = rel & 31;
        short4v o;
#pragma unroll
        for (int q = 0; q < 4; ++q)
            o[q] = f2bf(cw[((size_t)co * FINN + ci + q) * k + j]);
        *(short4v*)&WT[e] = o;
    } else if (bid < 9088) {
        int e = (bid - 8960) * 1024 + tid * 4;   // 131072 elems
        int n = e >> 10, kq = e & 1023;
        short4v o;
#pragma unroll
        for (int q = 0; q < 4; ++q) o[q] = f2bf(W1[(size_t)(kq + q) * HH + n]);
        *(short4v*)&W1T[e] = o;
    } else if (bid < 9104) {
        int e = (bid - 9088) * 1024 + tid * 4;   // 16384 elems
        int n = e >> 7, kq = e & 127;
        short4v o;
#pragma unroll
        for (int q = 0; q < 4; ++q) o[q] = f2bf(W2[(size_t)(kq + q) * HH + n]);
        *(short4v*)&W2T[e] = o;
    } else if (bid < 9120) {
        int e = (bid - 9104) * 1024 + tid * 4;
        int n = e >> 7, kq = e & 127;
        short4v o;
#pragma unroll
        for (int q = 0; q < 4; ++q) o[q] = f2bf(W3[(size_t)(kq + q) * HH + n]);
        *(short4v*)&W3T[e] = o;
    } else {
        int w = tid >> 6, lane = tid & 63;
        if (w < 3) {
            const float* p = (w == 0) ? p1 : (w == 1) ? p2 : p3;
            float v0 = p[lane], v1 = p[lane + 64];
            float s = wsum(v0 * v0 + v1 * v1);
            if (lane == 0) pnorm[w] = sqrtf(s);
        }
    }
}

// ---------------- SpMM + GCN epilogue + fused score ----------------
__global__ __launch_bounds__(256) void spmm_gcn(
    const float* __restrict__ A, const float* __restrict__ Hin,
    const float* __restrict__ dinv, const float* __restrict__ bias,
    const float* __restrict__ p, const float* __restrict__ pnorm,
    float* __restrict__ Gout, float* __restrict__ score, int n)
{
    int wid = (blockIdx.x * blockDim.x + threadIdx.x) >> 6;
    int lane = threadIdx.x & 63;
    int b = wid / n, row = wid % n;
    const float* Arow = A + ((size_t)b * n + row) * n;
    float acc0 = 0.f, acc1 = 0.f;
    for (int c = 0; c < n; c += 64) {
        float av = Arow[c + lane];
        unsigned long long mask = __ballot(av != 0.0f);
        while (mask) {
            int i = __ffsll((unsigned long long)mask) - 1;
            mask &= mask - 1;
            float val = __shfl(av, i, 64);
            const float* hr = Hin + ((size_t)b * n + c + i) * HH;
            acc0 = fmaf(val, hr[lane], acc0);
            acc1 = fmaf(val, hr[lane + 64], acc1);
        }
    }
    float dv = dinv[b * n + row];
    float g0 = fmaxf(fmaf(acc0, dv, bias[lane]), 0.f);
    float g1 = fmaxf(fmaf(acc1, dv, bias[lane + 64]), 0.f);
    float* gr = Gout + ((size_t)b * n + row) * HH;
    gr[lane] = g0;
    gr[lane + 64] = g1;
    float s = g0 * p[lane] + g1 * p[lane + 64];
    s = wsum(s);
    if (lane == 0) score[b * n + row] = tanhf(s / (pnorm[0] + 1e-12f));
}

// ---------------- per-batch top-k (bitonic, stable ties) ----------------
__global__ __launch_bounds__(256) void topk_kernel(
    const float* __restrict__ score, int* __restrict__ idx_out, int n, int k)
{
    __shared__ float sv[512];
    __shared__ int si[512];
    int b = blockIdx.x, tid = threadIdx.x;
    for (int j = tid; j < n; j += blockDim.x) { sv[j] = score[b * n + j]; si[j] = j; }
    __syncthreads();
    for (int sz = 2; sz <= n; sz <<= 1) {
        for (int st = sz >> 1; st; st >>= 1) {
            for (int t = tid; t < (n >> 1); t += blockDim.x) {
                int i = ((t / st) * (st << 1)) + (t % st);
                int j = i + st;
                float vi = sv[i], vj = sv[j];
                int ii = si[i], ij = si[j];
                bool descend = ((i & sz) == 0);
                bool igreater = (vi > vj) || (vi == vj && ii < ij);
                if (igreater != descend) {
                    sv[i] = vj; sv[j] = vi;
                    si[i] = ij; si[j] = ii;
                }
            }
            __syncthreads();
        }
    }
    for (int j = tid; j < k; j += blockDim.x) idx_out[b * k + j] = si[j];
}

// ---------------- induced subgraph gather + degree ----------------
__global__ __launch_bounds__(256) void gatherA_kernel(
    const float* __restrict__ Ain, const int* __restrict__ idx,
    float* __restrict__ Aout, float* __restrict__ dinv_out, int n, int k)
{
    int wid = (blockIdx.x * blockDim.x + threadIdx.x) >> 6;
    int lane = threadIdx.x & 63;
    int b = wid / k, i = wid % k;
    int isrc = idx[b * k + i];
    const float* src = Ain + ((size_t)b * n + isrc) * n;
    float s = 0.f;
    for (int c = lane; c < k; c += 64) {
        int jsrc = idx[b * k + c];
        float v = src[jsrc];
        Aout[((size_t)b * k + i) * k + c] = v;
        s += v;
    }
    s = wsum(s);
    if (lane == 0) dinv_out[b * k + i] = rsqrtf(s);
}

// ---------------- fused gatherX (score-gated) + readout ----------------
__global__ __launch_bounds__(256) void pool_finish(
    const float* __restrict__ G, const float* __restrict__ score,
    const int* __restrict__ idx, float* __restrict__ X, float* __restrict__ R,
    int n, int k, int first, int writex)
{
    __shared__ int lidx[256];
    __shared__ float lsc[256];
    __shared__ float ps[2][128], pm[2][128];
    int b = blockIdx.x, tid = threadIdx.x;
    for (int i = tid; i < k; i += 256) {
        int ii = idx[b * k + i];
        lidx[i] = ii;
        lsc[i] = score[b * n + ii];
    }
    __syncthreads();
    int h = tid & 127, half = tid >> 7;
    int i0 = half * (k >> 1), i1 = i0 + (k >> 1);
    float s = 0.f, m = -INFINITY;
    for (int i = i0; i < i1; ++i) {
        float v = G[((size_t)b * n + lidx[i]) * HH + h] * lsc[i];
        if (writex) X[((size_t)b * k + i) * HH + h] = v;
        s += v;
        m = fmaxf(m, v);
    }
    ps[half][h] = s;
    pm[half][h] = m;
    __syncthreads();
    if (tid < 128) {
        float st = ps[0][h] + ps[1][h];
        float mt = fmaxf(pm[0][h], pm[1][h]);
        float mean = st / (float)k;
        if (first) {
            R[b * 256 + h] = mean;
            R[b * 256 + 128 + h] = mt;
        } else {
            R[b * 256 + h] += mean;
            R[b * 256 + 128 + h] += mt;
        }
    }
}

// ---------------- conv shifted-sum + bias + relu + atomic global max ---------
// grid 64b x 4br x 8chunks = 2048 blocks. seq must be zeroed beforehand.
__global__ __launch_bounds__(256) void conv_reduce(
    const float* __restrict__ P,
    const float* __restrict__ cb0, const float* __restrict__ cb1,
    const float* __restrict__ cb2, const float* __restrict__ cb3,
    float* __restrict__ seq)
{
    int bid = blockIdx.x;
    int chunk = bid & 7, br = (bid >> 3) & 3, b = bid >> 5;
    int k = 3 + 2 * br;
    int base = (br == 0) ? 0 : (br == 1) ? 96 : (br == 2) ? 256 : 480;
    int T = LL - k + 1;
    int co = threadIdx.x & 31, ts = threadIdx.x >> 5;
    const float* cb = (br == 0) ? cb0 : (br == 1) ? cb1 : (br == 2) ? cb2 : cb3;
    float bias = cb[co];
    int c0 = chunk * 64;
    int cend = (c0 + 64 < T) ? c0 + 64 : T;
    float m = -INFINITY;
    for (int t = c0 + ts; t < cend; t += 8) {
        float acc = 0.f;
        for (int j = 0; j < k; ++j)
            acc += P[((size_t)b * LL + t + j) * 768 + base + j * 32 + co];
        m = fmaxf(m, acc + bias);
    }
    __shared__ float red[256];
    red[threadIdx.x] = m;
    __syncthreads();
    if (threadIdx.x < 32) {
        for (int s = 1; s < 8; ++s) m = fmaxf(m, red[co + s * 32]);
        atomicMax((int*)&seq[b * 128 + br * 32 + co], __float_as_int(fmaxf(m, 0.f)));
    }
}

// ---------------- fused MLP head: seq1 + gnn + gate + fc1 + fc2 + out --------
__global__ __launch_bounds__(256) void head_fused(
    const float* __restrict__ seq, const float* __restrict__ tf_w,
    const float* __restrict__ tf_b,
    const float* __restrict__ R, const float* __restrict__ cat_w,
    const float* __restrict__ cat_b,
    const float* __restrict__ w1_gate,
    const float* __restrict__ fc1_w, const float* __restrict__ fc1_b,
    const float* __restrict__ fc2_w, const float* __restrict__ fc2_b,
    const float* __restrict__ out_w, const float* __restrict__ out_b,
    float* __restrict__ out)
{
    int b = blockIdx.x, tid = threadIdx.x;
    __shared__ float sq[128], rr[256], g0[128], g1[512], g2[256];
    rr[tid] = R[b * 256 + tid];
    if (tid < 128) sq[tid] = seq[b * 128 + tid];
    __syncthreads();
    if (tid < 128) {
        float a = tf_b[tid];
        for (int i = 0; i < 128; ++i) a = fmaf(sq[i], tf_w[i * 128 + tid], a);
        float s1 = fmaxf(a, 0.f);
        float c = cat_b[tid];
        for (int i = 0; i < 256; ++i) c = fmaf(rr[i], cat_w[i * 128 + tid], c);
        float gn = fmaxf(c, 0.f);
        float w = 1.f / (1.f + expf(-w1_gate[0]));
        g0[tid] = (1.f - w) * gn + w * s1;
    }
    __syncthreads();
    for (int o = tid; o < 512; o += 256) {
        float a = fc1_b[o];
        for (int i = 0; i < 128; ++i) a = fmaf(g0[i], fc1_w[i * 512 + o], a);
        g1[o] = fmaxf(a, 0.f);
    }
    __syncthreads();
    {
        int o = tid;
        float a = fc2_b[o];
        for (int i = 0; i < 512; ++i) a = fmaf(g1[i], fc2_w[i * 256 + o], a);
        g2[o] = fmaxf(a, 0.f);
    }
    __syncthreads();
    if (tid < 64) {
        float a0 = 0.f, a1 = 0.f;
        for (int q = tid; q < 256; q += 64) {
            a0 = fmaf(g2[q], out_w[q * 2 + 0], a0);
            a1 = fmaf(g2[q], out_w[q * 2 + 1], a1);
        }
        a0 = wsum(a0);
        a1 = wsum(a1);
        if (tid == 0) {
            float l0 = fmaxf(a0 + out_b[0], 0.f);
            float l1 = fmaxf(a1 + out_b[1], 0.f);
            float mm = fmaxf(l0, l1);
            float e0 = expf(l0 - mm), e1 = expf(l1 - mm);
            float d = e0 + e1;
            out[b * 2 + 0] = e0 / d;
            out[b * 2 + 1] = e1 / d;
        }
    }
}

// =======================================================================
extern "C" void kernel_launch(void* const* d_in, const int* in_sizes, int n_in,
                              void* d_out, int out_size, void* d_ws, size_t ws_size,
                              hipStream_t stream)
{
    const float* adj      = (const float*)d_in[0];
    const float* feat     = (const float*)d_in[1];
    const float* pad_dmap = (const float*)d_in[2];
    const float* W1 = (const float*)d_in[3];
    const float* b1 = (const float*)d_in[4];
    const float* p1 = (const float*)d_in[5];
    const float* W2 = (const float*)d_in[6];
    const float* b2 = (const float*)d_in[7];
    const float* p2 = (const float*)d_in[8];
    const float* W3 = (const float*)d_in[9];
    const float* b3 = (const float*)d_in[10];
    const float* p3 = (const float*)d_in[11];
    const float* cat_w = (const float*)d_in[12];
    const float* cat_b = (const float*)d_in[13];
    const float* cw0 = (const float*)d_in[14];
    const float* cb0 = (const float*)d_in[15];
    const float* cw1 = (const float*)d_in[16];
    const float* cb1 = (const float*)d_in[17];
    const float* cw2 = (const float*)d_in[18];
    const float* cb2 = (const float*)d_in[19];
    const float* cw3 = (const float*)d_in[20];
    const float* cb3 = (const float*)d_in[21];
    const float* tf_w = (const float*)d_in[22];
    const float* tf_b = (const float*)d_in[23];
    const float* w1_gate = (const float*)d_in[24];
    const float* fc1_w = (const float*)d_in[25];
    const float* fc1_b = (const float*)d_in[26];
    const float* fc2_w = (const float*)d_in[27];
    const float* fc2_b = (const float*)d_in[28];
    const float* out_w = (const float*)d_in[29];
    const float* out_b = (const float*)d_in[30];
    float* out = (float*)d_out;

    char* ws = (char*)d_ws;
    auto al = [](size_t x) { return (x + 255) & ~(size_t)255; };
    size_t off = 0;
    auto alloc = [&](size_t nbytes) { size_t o = off; off += al(nbytes); return o; };

    // persistent small buffers
    float* pnorm  = (float*)(ws + alloc(3 * 4));
    float* dinv1  = (float*)(ws + alloc((size_t)B64 * NN * 4));
    float* score1 = (float*)(ws + alloc((size_t)B64 * NN * 4));
    int*   idx1   = (int*)  (ws + alloc((size_t)B64 * KK1 * 4));
    float* dinv2  = (float*)(ws + alloc((size_t)B64 * KK1 * 4));
    float* score2 = (float*)(ws + alloc((size_t)B64 * KK1 * 4));
    int*   idx2   = (int*)  (ws + alloc((size_t)B64 * KK2 * 4));
    float* dinv3  = (float*)(ws + alloc((size_t)B64 * KK2 * 4));
    float* score3 = (float*)(ws + alloc((size_t)B64 * KK2 * 4));
    int*   idx3   = (int*)  (ws + alloc((size_t)B64 * KK3 * 4));
    float* R      = (float*)(ws + alloc((size_t)B64 * 256 * 4));
    float* seq    = (float*)(ws + alloc((size_t)B64 * 128 * 4));
    short* W1T    = (short*)(ws + alloc((size_t)HH * FINN * 2));
    short* W2T    = (short*)(ws + alloc((size_t)HH * HH * 2));
    short* W3T    = (short*)(ws + alloc((size_t)HH * HH * 2));

    // big region: CNN phase aliases GNN phase (CNN completes first)
    size_t big = off;
    short* WT = (short*)(ws + big);
    size_t cnnoff = big + al((size_t)768 * FINN * 2);
    float* P = (float*)(ws + cnnoff);
    size_t cnn_end = cnnoff + al((size_t)B64 * LL * 768 * 4);
    size_t g = big;
    float* HT = (float*)(ws + g); g += al((size_t)B64 * NN * HH * 4);
    float* G  = (float*)(ws + g); g += al((size_t)B64 * NN * HH * 4);
    float* A1 = (float*)(ws + g); g += al((size_t)B64 * KK1 * KK1 * 4);
    float* X1 = (float*)(ws + g); g += al((size_t)B64 * KK1 * HH * 4);
    float* A2 = (float*)(ws + g); g += al((size_t)B64 * KK2 * KK2 * 4);
    float* X2 = (float*)(ws + g); g += al((size_t)B64 * KK2 * HH * 4);
    size_t gnn_end = g;
    size_t need = (cnn_end > gnn_end) ? cnn_end : gnn_end;
    if (ws_size < need) return;

    // seq accumulated via atomicMax on non-negative floats -> zero-init
    hipMemsetAsync(seq, 0, (size_t)B64 * 128 * 4, stream);

    // prep: rowsum + all bf16 weight packs + pnorm
    prep_kernel<<<9121, 256, 0, stream>>>(adj, dinv1, cw0, cw1, cw2, cw3, WT,
                                          W1, W1T, W2, W2T, W3, W3T,
                                          p1, p2, p3, pnorm);

    // CNN phase: P = pad_dmap @ Wcat (bf16 MFMA, XCD-swizzled), then reduce
    mfma_gemm<<<1536, 256, 0, stream>>>(pad_dmap, WT, P, B64 * LL, 768, FINN,
                                        nullptr, 6, 1);
    conv_reduce<<<2048, 256, 0, stream>>>(P, cb0, cb1, cb2, cb3, seq);

    // GNN stage 1
    mfma_gemm<<<256, 256, 0, stream>>>(feat, W1T, HT, B64 * NN, HH, FINN,
                                       dinv1, 1, 0);
    spmm_gcn<<<(B64 * NN) / 4, 256, 0, stream>>>(adj, HT, dinv1, b1, p1, pnorm + 0,
                                                 G, score1, NN);
    topk_kernel<<<B64, 256, 0, stream>>>(score1, idx1, NN, KK1);
    gatherA_kernel<<<(B64 * KK1) / 4, 256, 0, stream>>>(adj, idx1, A1, dinv2, NN, KK1);
    pool_finish<<<B64, 256, 0, stream>>>(G, score1, idx1, X1, R, NN, KK1, 1, 1);

    // GNN stage 2
    mfma_gemm<<<128, 256, 0, stream>>>(X1, W2T, HT, B64 * KK1, HH, HH,
                                       dinv2, 1, 0);
    spmm_gcn<<<(B64 * KK1) / 4, 256, 0, stream>>>(A1, HT, dinv2, b2, p2, pnorm + 1,
                                                  G, score2, KK1);
    topk_kernel<<<B64, 256, 0, stream>>>(score2, idx2, KK1, KK2);
    gatherA_kernel<<<(B64 * KK2) / 4, 256, 0, stream>>>(A1, idx2, A2, dinv3, KK1, KK2);
    pool_finish<<<B64, 256, 0, stream>>>(G, score2, idx2, X2, R, KK1, KK2, 0, 1);

    // GNN stage 3 (A3 never used; X3 only feeds readout -> writex=0)
    mfma_gemm<<<64, 256, 0, stream>>>(X2, W3T, HT, B64 * KK2, HH, HH,
                                      dinv3, 1, 0);
    spmm_gcn<<<(B64 * KK2) / 4, 256, 0, stream>>>(A2, HT, dinv3, b3, p3, pnorm + 2,
                                                  G, score3, KK2);
    topk_kernel<<<B64, 256, 0, stream>>>(score3, idx3, KK2, KK3);
    pool_finish<<<B64, 256, 0, stream>>>(G, score3, idx3, nullptr, R, KK2, KK3, 0, 0);

    // fused MLP head
    head_fused<<<B64, 256, 0, stream>>>(seq, tf_w, tf_b, R, cat_w, cat_b, w1_gate,
                                        fc1_w, fc1_b, fc2_w, fc2_b, out_w, out_b,
                                        out);
}

// Round 6
// 755.697 us; speedup vs baseline: 2.0412x; 1.0624x over previous
//
#include <hip/hip_runtime.h>
#include <math.h>

// Problem constants (from reference)
#define B64  64
#define NN   512
#define FINN 1024
#define HH   128
#define LL   512
#define KK1  256
#define KK2  128
#define KK3  64

typedef __attribute__((ext_vector_type(8))) short short8v;
typedef __attribute__((ext_vector_type(4))) short short4v;
typedef __attribute__((ext_vector_type(4))) float f32x4;

// ---------------- helpers ----------------
__device__ __forceinline__ float wsum(float v) {
#pragma unroll
    for (int off = 32; off; off >>= 1) v += __shfl_xor(v, off, 64);
    return v;
}

__device__ __forceinline__ short f2bf(float x) {
    union { float f; unsigned u; } v; v.f = x;
    unsigned r = v.u + 0x7fffu + ((v.u >> 16) & 1u);  // RNE
    return (short)(r >> 16);
}

#define LDAP 40

// ---------------- bf16 MFMA GEMM (CNN branch) ----------------
__global__ __launch_bounds__(256) void mfma_gemm(
    const float* __restrict__ A, const short* __restrict__ BT,
    float* __restrict__ C, int M, int N, int K,
    const float* __restrict__ rowscale, int ntx, int swz)
{
    __shared__ short As[128 * LDAP];
    __shared__ short Bs[128 * LDAP];
    int bid = blockIdx.x;
    if (swz) bid = (bid & 7) * (gridDim.x >> 3) + (bid >> 3);
    const int m0 = (bid / ntx) * 128;
    const int n0 = (bid % ntx) * 128;
    const int tid = threadIdx.x;
    const int lane = tid & 63;
    const int wid = tid >> 6;
    const int wr = (wid >> 1) * 64;
    const int wc = (wid & 1) * 64;

    f32x4 acc[4][4];
#pragma unroll
    for (int i = 0; i < 4; ++i)
#pragma unroll
        for (int j = 0; j < 4; ++j) acc[i][j] = (f32x4){0.f, 0.f, 0.f, 0.f};

    const int srow = tid >> 1;
    const int skq = (tid & 1) * 16;
    const float* Aptr = A + (size_t)(m0 + srow) * K + skq;
    const short* Bptr = BT + (size_t)(n0 + srow) * K + skq;

    const int fr = lane & 15;
    const int fk = (lane >> 4) * 8;
    const int crow = (lane >> 4) * 4;

    for (int k0 = 0; k0 < K; k0 += 32) {
        float4 fa0 = *(const float4*)(Aptr + k0);
        float4 fa1 = *(const float4*)(Aptr + k0 + 4);
        float4 fa2 = *(const float4*)(Aptr + k0 + 8);
        float4 fa3 = *(const float4*)(Aptr + k0 + 12);
        float4 fb0 = *(const float4*)(Bptr + k0);
        float4 fb1 = *(const float4*)(Bptr + k0 + 8);
        __syncthreads();
        short8v ha, hb;
        ha[0] = f2bf(fa0.x); ha[1] = f2bf(fa0.y); ha[2] = f2bf(fa0.z); ha[3] = f2bf(fa0.w);
        ha[4] = f2bf(fa1.x); ha[5] = f2bf(fa1.y); ha[6] = f2bf(fa1.z); ha[7] = f2bf(fa1.w);
        hb[0] = f2bf(fa2.x); hb[1] = f2bf(fa2.y); hb[2] = f2bf(fa2.z); hb[3] = f2bf(fa2.w);
        hb[4] = f2bf(fa3.x); hb[5] = f2bf(fa3.y); hb[6] = f2bf(fa3.z); hb[7] = f2bf(fa3.w);
        *(short8v*)&As[srow * LDAP + skq] = ha;
        *(short8v*)&As[srow * LDAP + skq + 8] = hb;
        *(short8v*)&Bs[srow * LDAP + skq] = *(const short8v*)&fb0;
        *(short8v*)&Bs[srow * LDAP + skq + 8] = *(const short8v*)&fb1;
        __syncthreads();

        short8v af[4], bfr[4];
#pragma unroll
        for (int i = 0; i < 4; ++i) {
            af[i] = *(const short8v*)&As[(wr + i * 16 + fr) * LDAP + fk];
            bfr[i] = *(const short8v*)&Bs[(wc + i * 16 + fr) * LDAP + fk];
        }
#pragma unroll
        for (int mi = 0; mi < 4; ++mi)
#pragma unroll
            for (int ni = 0; ni < 4; ++ni)
                acc[mi][ni] = __builtin_amdgcn_mfma_f32_16x16x32_bf16(
                    af[mi], bfr[ni], acc[mi][ni], 0, 0, 0);
    }

#pragma unroll
    for (int mi = 0; mi < 4; ++mi) {
#pragma unroll
        for (int ni = 0; ni < 4; ++ni) {
            int col = n0 + wc + ni * 16 + fr;
#pragma unroll
            for (int r = 0; r < 4; ++r) {
                int row = m0 + wr + mi * 16 + crow + r;
                float v = acc[mi][ni][r];
                if (rowscale) v *= rowscale[row];
                C[(size_t)row * N + col] = v;
            }
        }
    }
}

// ---------------- tgemm: transposed-H GCN GEMM ----------------
// C[f][node] (per batch) = sum_k A_bf16[f][k] * Bt_f32[node][k]
// A: bf16 rows of length K (weightsT if a_per_batch=0, Ht[b] if 1)
// Bt: fp32 rows, global row index = n0+srow (works for feat/X/adj/A1/A2)
// EPI 0 (proj):  out bf16 Ht[b][128][npb],  v = acc * dinv[node]
// EPI 1 (aggr):  out fp32 Gt[b][128][npb],  v = relu(acc*dinv[node]+bias[f])
template <int EPI>
__global__ __launch_bounds__(256) void tgemm(
    const short* __restrict__ A, const float* __restrict__ Bt,
    void* __restrict__ Cout, int K, int npb, int a_per_batch,
    const float* __restrict__ dinv, const float* __restrict__ bias)
{
    __shared__ short As[128 * LDAP];
    __shared__ short Bs[128 * LDAP];
    const int n0 = blockIdx.x * 128;
    const int b = n0 / npb;
    const int nloc = n0 - b * npb;
    const int tid = threadIdx.x;
    const int lane = tid & 63;
    const int wid = tid >> 6;
    const int wr = (wid >> 1) * 64;   // f direction
    const int wc = (wid & 1) * 64;    // node direction

    f32x4 acc[4][4];
#pragma unroll
    for (int i = 0; i < 4; ++i)
#pragma unroll
        for (int j = 0; j < 4; ++j) acc[i][j] = (f32x4){0.f, 0.f, 0.f, 0.f};

    const int srow = tid >> 1;
    const int skq = (tid & 1) * 16;
    const short* Aptr = A + (size_t)((a_per_batch ? b * 128 : 0) + srow) * K + skq;
    const float* Bptr = Bt + (size_t)(n0 + srow) * K + skq;

    const int fr = lane & 15;
    const int fk = (lane >> 4) * 8;
    const int crow = (lane >> 4) * 4;

    for (int k0 = 0; k0 < K; k0 += 32) {
        short8v a0 = *(const short8v*)(Aptr + k0);
        short8v a1 = *(const short8v*)(Aptr + k0 + 8);
        float4 fb0 = *(const float4*)(Bptr + k0);
        float4 fb1 = *(const float4*)(Bptr + k0 + 4);
        float4 fb2 = *(const float4*)(Bptr + k0 + 8);
        float4 fb3 = *(const float4*)(Bptr + k0 + 12);
        __syncthreads();
        short8v hb0, hb1;
        hb0[0] = f2bf(fb0.x); hb0[1] = f2bf(fb0.y); hb0[2] = f2bf(fb0.z); hb0[3] = f2bf(fb0.w);
        hb0[4] = f2bf(fb1.x); hb0[5] = f2bf(fb1.y); hb0[6] = f2bf(fb1.z); hb0[7] = f2bf(fb1.w);
        hb1[0] = f2bf(fb2.x); hb1[1] = f2bf(fb2.y); hb1[2] = f2bf(fb2.z); hb1[3] = f2bf(fb2.w);
        hb1[4] = f2bf(fb3.x); hb1[5] = f2bf(fb3.y); hb1[6] = f2bf(fb3.z); hb1[7] = f2bf(fb3.w);
        *(short8v*)&As[srow * LDAP + skq] = a0;
        *(short8v*)&As[srow * LDAP + skq + 8] = a1;
        *(short8v*)&Bs[srow * LDAP + skq] = hb0;
        *(short8v*)&Bs[srow * LDAP + skq + 8] = hb1;
        __syncthreads();

        short8v af[4], bfr[4];
#pragma unroll
        for (int i = 0; i < 4; ++i) {
            af[i] = *(const short8v*)&As[(wr + i * 16 + fr) * LDAP + fk];
            bfr[i] = *(const short8v*)&Bs[(wc + i * 16 + fr) * LDAP + fk];
        }
#pragma unroll
        for (int mi = 0; mi < 4; ++mi)
#pragma unroll
            for (int ni = 0; ni < 4; ++ni)
                acc[mi][ni] = __builtin_amdgcn_mfma_f32_16x16x32_bf16(
                    af[mi], bfr[ni], acc[mi][ni], 0, 0, 0);
    }

#pragma unroll
    for (int mi = 0; mi < 4; ++mi) {
#pragma unroll
        for (int ni = 0; ni < 4; ++ni) {
            int node_t = wc + ni * 16 + fr;
            float dv = dinv[n0 + node_t];
#pragma unroll
            for (int r = 0; r < 4; ++r) {
                int f = wr + mi * 16 + crow + r;
                size_t oidx = ((size_t)(b * 128 + f)) * npb + nloc + node_t;
                float v = acc[mi][ni][r] * dv;
                if constexpr (EPI == 0) {
                    ((short*)Cout)[oidx] = f2bf(v);
                } else {
                    ((float*)Cout)[oidx] = fmaxf(v + bias[f], 0.f);
                }
            }
        }
    }
}

// ---------------- prep: rowsum + weight packs + pnorm (one dispatch) ---------
__global__ __launch_bounds__(256) void prep_kernel(
    const float* __restrict__ adj, float* __restrict__ dinv,
    const float* __restrict__ cw0, const float* __restrict__ cw1,
    const float* __restrict__ cw2, const float* __restrict__ cw3,
    short* __restrict__ WT,
    const float* __restrict__ W1, short* __restrict__ W1T,
    const float* __restrict__ W2, short* __restrict__ W2T,
    const float* __restrict__ W3, short* __restrict__ W3T,
    const float* __restrict__ p1, const float* __restrict__ p2,
    const float* __restrict__ p3, float* __restrict__ pnorm)
{
    const int bid = blockIdx.x, tid = threadIdx.x;
    if (bid < 8192) {
        int wid = (bid * 256 + tid) >> 6;
        int lane = tid & 63;
        const float* Arow = adj + (size_t)wid * NN;
        float s = 0.f;
        for (int c = lane; c < NN; c += 64) s += Arow[c];
        s = wsum(s);
        if (lane == 0) dinv[wid] = (s > 0.f) ? rsqrtf(s) : 0.f;
    } else if (bid < 8960) {
        int e = (bid - 8192) * 1024 + tid * 4;
        int col = e >> 10, ci = e & 1023;
        const float* cw; int k, base;
        if (col < 96)       { cw = cw0; k = 3; base = 0; }
        else if (col < 256) { cw = cw1; k = 5; base = 96; }
        else if (col < 480) { cw = cw2; k = 7; base = 256; }
        else                { cw = cw3; k = 9; base = 480; }
        int rel = col - base;
        int j = rel >> 5, co = rel & 31;
        short4v o;
#pragma unroll
        for (int q = 0; q < 4; ++q)
            o[q] = f2bf(cw[((size_t)co * FINN + ci + q) * k + j]);
        *(short4v*)&WT[e] = o;
    } else if (bid < 9088) {
        int e = (bid - 8960) * 1024 + tid * 4;
        int n = e >> 10, kq = e & 1023;
        short4v o;
#pragma unroll
        for (int q = 0; q < 4; ++q) o[q] = f2bf(W1[(size_t)(kq + q) * HH + n]);
        *(short4v*)&W1T[e] = o;
    } else if (bid < 9104) {
        int e = (bid - 9088) * 1024 + tid * 4;
        int n = e >> 7, kq = e & 127;
        short4v o;
#pragma unroll
        for (int q = 0; q < 4; ++q) o[q] = f2bf(W2[(size_t)(kq + q) * HH + n]);
        *(short4v*)&W2T[e] = o;
    } else if (bid < 9120) {
        int e = (bid - 9104) * 1024 + tid * 4;
        int n = e >> 7, kq = e & 127;
        short4v o;
#pragma unroll
        for (int q = 0; q < 4; ++q) o[q] = f2bf(W3[(size_t)(kq + q) * HH + n]);
        *(short4v*)&W3T[e] = o;
    } else {
        int w = tid >> 6, lane = tid & 63;
        if (w < 3) {
            const float* p = (w == 0) ? p1 : (w == 1) ? p2 : p3;
            float v0 = p[lane], v1 = p[lane + 64];
            float s = wsum(v0 * v0 + v1 * v1);
            if (lane == 0) pnorm[w] = sqrtf(s);
        }
    }
}

// ---------------- fused score + top-k + gather/gate + readout ----------------
// Gt[b][128][npb] (fp32, transposed G). score[j]=tanh(dot_f(Gt[:,j],p)/pnorm).
// Bitonic sort (desc, stable ties) -> top-k. X[i][f]=Gt[f][idx_i]*score_i.
// Readout mean+max accumulated into R[b][256].
__global__ __launch_bounds__(256) void score_topk_pool(
    const float* __restrict__ Gt, const float* __restrict__ p,
    const float* __restrict__ pnorm, int* __restrict__ idx_out,
    float* __restrict__ X, float* __restrict__ R,
    int npb, int k, int first, int writex)
{
    __shared__ float sv[512];
    __shared__ int si[512];
    __shared__ float pp[128];
    __shared__ float ps[2][128], pm[2][128];
    int b = blockIdx.x, tid = threadIdx.x;
    if (tid < 128) pp[tid] = p[tid];
    __syncthreads();
    const float* Gb = Gt + (size_t)b * 128 * npb;
    float pn = pnorm[0] + 1e-12f;
    for (int j = tid; j < npb; j += 256) {
        float s = 0.f;
#pragma unroll 4
        for (int f = 0; f < 128; ++f) s = fmaf(Gb[(size_t)f * npb + j], pp[f], s);
        sv[j] = tanhf(s / pn);
        si[j] = j;
    }
    __syncthreads();
    // bitonic sort descending, stable
    for (int sz = 2; sz <= npb; sz <<= 1) {
        for (int st = sz >> 1; st; st >>= 1) {
            for (int t = tid; t < (npb >> 1); t += 256) {
                int i = ((t / st) * (st << 1)) + (t % st);
                int j = i + st;
                float vi = sv[i], vj = sv[j];
                int ii = si[i], ij = si[j];
                bool descend = ((i & sz) == 0);
                bool igreater = (vi > vj) || (vi == vj && ii < ij);
                if (igreater != descend) {
                    sv[i] = vj; sv[j] = vi;
                    si[i] = ij; si[j] = ii;
                }
            }
            __syncthreads();
        }
    }
    for (int j = tid; j < k; j += 256) idx_out[b * k + j] = si[j];
    // pool + readout
    int f = tid & 127, iset = tid >> 7;
    float s = 0.f, m = -INFINITY;
    for (int i = iset; i < k; i += 2) {
        float v = Gb[(size_t)f * npb + si[i]] * sv[i];
        if (writex) X[((size_t)b * k + i) * HH + f] = v;
        s += v;
        m = fmaxf(m, v);
    }
    ps[iset][f] = s;
    pm[iset][f] = m;
    __syncthreads();
    if (tid < 128) {
        float st = ps[0][f] + ps[1][f];
        float mt = fmaxf(pm[0][f], pm[1][f]);
        float mean = st / (float)k;
        if (first) {
            R[b * 256 + f] = mean;
            R[b * 256 + 128 + f] = mt;
        } else {
            R[b * 256 + f] += mean;
            R[b * 256 + 128 + f] += mt;
        }
    }
}

// ---------------- induced subgraph gather + degree ----------------
__global__ __launch_bounds__(256) void gatherA_kernel(
    const float* __restrict__ Ain, const int* __restrict__ idx,
    float* __restrict__ Aout, float* __restrict__ dinv_out, int n, int k)
{
    int wid = (blockIdx.x * blockDim.x + threadIdx.x) >> 6;
    int lane = threadIdx.x & 63;
    int b = wid / k, i = wid % k;
    int isrc = idx[b * k + i];
    const float* src = Ain + ((size_t)b * n + isrc) * n;
    float s = 0.f;
    for (int c = lane; c < k; c += 64) {
        int jsrc = idx[b * k + c];
        float v = src[jsrc];
        Aout[((size_t)b * k + i) * k + c] = v;
        s += v;
    }
    s = wsum(s);
    if (lane == 0) dinv_out[b * k + i] = rsqrtf(s);
}

// ---------------- conv shifted-sum + bias + relu + atomic global max ---------
__global__ __launch_bounds__(256) void conv_reduce(
    const float* __restrict__ P,
    const float* __restrict__ cb0, const float* __restrict__ cb1,
    const float* __restrict__ cb2, const float* __restrict__ cb3,
    float* __restrict__ seq)
{
    int bid = blockIdx.x;
    int chunk = bid & 7, br = (bid >> 3) & 3, b = bid >> 5;
    int k = 3 + 2 * br;
    int base = (br == 0) ? 0 : (br == 1) ? 96 : (br == 2) ? 256 : 480;
    int T = LL - k + 1;
    int co = threadIdx.x & 31, ts = threadIdx.x >> 5;
    const float* cb = (br == 0) ? cb0 : (br == 1) ? cb1 : (br == 2) ? cb2 : cb3;
    float bias = cb[co];
    int c0 = chunk * 64;
    int cend = (c0 + 64 < T) ? c0 + 64 : T;
    float m = -INFINITY;
    for (int t = c0 + ts; t < cend; t += 8) {
        float acc = 0.f;
        for (int j = 0; j < k; ++j)
            acc += P[((size_t)b * LL + t + j) * 768 + base + j * 32 + co];
        m = fmaxf(m, acc + bias);
    }
    __shared__ float red[256];
    red[threadIdx.x] = m;
    __syncthreads();
    if (threadIdx.x < 32) {
        for (int s = 1; s < 8; ++s) m = fmaxf(m, red[co + s * 32]);
        atomicMax((int*)&seq[b * 128 + br * 32 + co], __float_as_int(fmaxf(m, 0.f)));
    }
}

// ---------------- fused MLP head ----------------
__global__ __launch_bounds__(256) void head_fused(
    const float* __restrict__ seq, const float* __restrict__ tf_w,
    const float* __restrict__ tf_b,
    const float* __restrict__ R, const float* __restrict__ cat_w,
    const float* __restrict__ cat_b,
    const float* __restrict__ w1_gate,
    const float* __restrict__ fc1_w, const float* __restrict__ fc1_b,
    const float* __restrict__ fc2_w, const float* __restrict__ fc2_b,
    const float* __restrict__ out_w, const float* __restrict__ out_b,
    float* __restrict__ out)
{
    int b = blockIdx.x, tid = threadIdx.x;
    __shared__ float sq[128], rr[256], g0[128], g1[512], g2[256];
    rr[tid] = R[b * 256 + tid];
    if (tid < 128) sq[tid] = seq[b * 128 + tid];
    __syncthreads();
    if (tid < 128) {
        float a = tf_b[tid];
        for (int i = 0; i < 128; ++i) a = fmaf(sq[i], tf_w[i * 128 + tid], a);
        float s1 = fmaxf(a, 0.f);
        float c = cat_b[tid];
        for (int i = 0; i < 256; ++i) c = fmaf(rr[i], cat_w[i * 128 + tid], c);
        float gn = fmaxf(c, 0.f);
        float w = 1.f / (1.f + expf(-w1_gate[0]));
        g0[tid] = (1.f - w) * gn + w * s1;
    }
    __syncthreads();
    for (int o = tid; o < 512; o += 256) {
        float a = fc1_b[o];
        for (int i = 0; i < 128; ++i) a = fmaf(g0[i], fc1_w[i * 512 + o], a);
        g1[o] = fmaxf(a, 0.f);
    }
    __syncthreads();
    {
        int o = tid;
        float a = fc2_b[o];
        for (int i = 0; i < 512; ++i) a = fmaf(g1[i], fc2_w[i * 256 + o], a);
        g2[o] = fmaxf(a, 0.f);
    }
    __syncthreads();
    if (tid < 64) {
        float a0 = 0.f, a1 = 0.f;
        for (int q = tid; q < 256; q += 64) {
            a0 = fmaf(g2[q], out_w[q * 2 + 0], a0);
            a1 = fmaf(g2[q], out_w[q * 2 + 1], a1);
        }
        a0 = wsum(a0);
        a1 = wsum(a1);
        if (tid == 0) {
            float l0 = fmaxf(a0 + out_b[0], 0.f);
            float l1 = fmaxf(a1 + out_b[1], 0.f);
            float mm = fmaxf(l0, l1);
            float e0 = expf(l0 - mm), e1 = expf(l1 - mm);
            float d = e0 + e1;
            out[b * 2 + 0] = e0 / d;
            out[b * 2 + 1] = e1 / d;
        }
    }
}

// =======================================================================
extern "C" void kernel_launch(void* const* d_in, const int* in_sizes, int n_in,
                              void* d_out, int out_size, void* d_ws, size_t ws_size,
                              hipStream_t stream)
{
    const float* adj      = (const float*)d_in[0];
    const float* feat     = (const float*)d_in[1];
    const float* pad_dmap = (const float*)d_in[2];
    const float* W1 = (const float*)d_in[3];
    const float* b1 = (const float*)d_in[4];
    const float* p1 = (const float*)d_in[5];
    const float* W2 = (const float*)d_in[6];
    const float* b2 = (const float*)d_in[7];
    const float* p2 = (const float*)d_in[8];
    const float* W3 = (const float*)d_in[9];
    const float* b3 = (const float*)d_in[10];
    const float* p3 = (const float*)d_in[11];
    const float* cat_w = (const float*)d_in[12];
    const float* cat_b = (const float*)d_in[13];
    const float* cw0 = (const float*)d_in[14];
    const float* cb0 = (const float*)d_in[15];
    const float* cw1 = (const float*)d_in[16];
    const float* cb1 = (const float*)d_in[17];
    const float* cw2 = (const float*)d_in[18];
    const float* cb2 = (const float*)d_in[19];
    const float* cw3 = (const float*)d_in[20];
    const float* cb3 = (const float*)d_in[21];
    const float* tf_w = (const float*)d_in[22];
    const float* tf_b = (const float*)d_in[23];
    const float* w1_gate = (const float*)d_in[24];
    const float* fc1_w = (const float*)d_in[25];
    const float* fc1_b = (const float*)d_in[26];
    const float* fc2_w = (const float*)d_in[27];
    const float* fc2_b = (const float*)d_in[28];
    const float* out_w = (const float*)d_in[29];
    const float* out_b = (const float*)d_in[30];
    float* out = (float*)d_out;

    char* ws = (char*)d_ws;
    auto al = [](size_t x) { return (x + 255) & ~(size_t)255; };
    size_t off = 0;
    auto alloc = [&](size_t nbytes) { size_t o = off; off += al(nbytes); return o; };

    // persistent small buffers
    float* pnorm  = (float*)(ws + alloc(3 * 4));
    float* dinv1  = (float*)(ws + alloc((size_t)B64 * NN * 4));
    float* dinv2  = (float*)(ws + alloc((size_t)B64 * KK1 * 4));
    float* dinv3  = (float*)(ws + alloc((size_t)B64 * KK2 * 4));
    int*   idx1   = (int*)  (ws + alloc((size_t)B64 * KK1 * 4));
    int*   idx2   = (int*)  (ws + alloc((size_t)B64 * KK2 * 4));
    int*   idx3   = (int*)  (ws + alloc((size_t)B64 * KK3 * 4));
    float* R      = (float*)(ws + alloc((size_t)B64 * 256 * 4));
    float* seq    = (float*)(ws + alloc((size_t)B64 * 128 * 4));
    short* W1T    = (short*)(ws + alloc((size_t)HH * FINN * 2));
    short* W2T    = (short*)(ws + alloc((size_t)HH * HH * 2));
    short* W3T    = (short*)(ws + alloc((size_t)HH * HH * 2));

    // big region: CNN phase aliases GNN phase (CNN completes first)
    size_t big = off;
    // CNN
    short* WT = (short*)(ws + big);
    size_t cnnoff = big + al((size_t)768 * FINN * 2);
    float* P = (float*)(ws + cnnoff);
    size_t cnn_end = cnnoff + al((size_t)B64 * LL * 768 * 4);
    // GNN (aliased)
    size_t g = big;
    short* Ht1 = (short*)(ws + g); g += al((size_t)B64 * HH * NN * 2);
    float* Gt1 = (float*)(ws + g); g += al((size_t)B64 * HH * NN * 4);
    float* A1  = (float*)(ws + g); g += al((size_t)B64 * KK1 * KK1 * 4);
    float* X1  = (float*)(ws + g); g += al((size_t)B64 * KK1 * HH * 4);
    short* Ht2 = (short*)(ws + g); g += al((size_t)B64 * HH * KK1 * 2);
    float* Gt2 = (float*)(ws + g); g += al((size_t)B64 * HH * KK1 * 4);
    float* A2  = (float*)(ws + g); g += al((size_t)B64 * KK2 * KK2 * 4);
    float* X2  = (float*)(ws + g); g += al((size_t)B64 * KK2 * HH * 4);
    short* Ht3 = (short*)(ws + g); g += al((size_t)B64 * HH * KK2 * 2);
    float* Gt3 = (float*)(ws + g); g += al((size_t)B64 * HH * KK2 * 4);
    size_t gnn_end = g;
    size_t need = (cnn_end > gnn_end) ? cnn_end : gnn_end;
    if (ws_size < need) return;

    hipMemsetAsync(seq, 0, (size_t)B64 * 128 * 4, stream);

    // prep: rowsum + bf16 weight packs + pnorm
    prep_kernel<<<9121, 256, 0, stream>>>(adj, dinv1, cw0, cw1, cw2, cw3, WT,
                                          W1, W1T, W2, W2T, W3, W3T,
                                          p1, p2, p3, pnorm);

    // CNN phase
    mfma_gemm<<<1536, 256, 0, stream>>>(pad_dmap, WT, P, B64 * LL, 768, FINN,
                                        nullptr, 6, 1);
    conv_reduce<<<2048, 256, 0, stream>>>(P, cb0, cb1, cb2, cb3, seq);

    // GNN stage 1: Ht1 = (W1T @ feat^T)*dinv1 ; Gt1 = relu((Ht1@adj)*dinv1+b1)
    tgemm<0><<<256, 256, 0, stream>>>(W1T, feat, Ht1, FINN, NN, 0, dinv1, nullptr);
    tgemm<1><<<256, 256, 0, stream>>>(Ht1, adj, Gt1, NN, NN, 1, dinv1, b1);
    score_topk_pool<<<B64, 256, 0, stream>>>(Gt1, p1, pnorm + 0, idx1, X1, R,
                                             NN, KK1, 1, 1);
    gatherA_kernel<<<(B64 * KK1) / 4, 256, 0, stream>>>(adj, idx1, A1, dinv2, NN, KK1);

    // GNN stage 2
    tgemm<0><<<128, 256, 0, stream>>>(W2T, X1, Ht2, HH, KK1, 0, dinv2, nullptr);
    tgemm<1><<<128, 256, 0, stream>>>(Ht2, A1, Gt2, KK1, KK1, 1, dinv2, b2);
    score_topk_pool<<<B64, 256, 0, stream>>>(Gt2, p2, pnorm + 1, idx2, X2, R,
                                             KK1, KK2, 0, 1);
    gatherA_kernel<<<(B64 * KK2) / 4, 256, 0, stream>>>(A1, idx2, A2, dinv3, KK1, KK2);

    // GNN stage 3
    tgemm<0><<<64, 256, 0, stream>>>(W3T, X2, Ht3, HH, KK2, 0, dinv3, nullptr);
    tgemm<1><<<64, 256, 0, stream>>>(Ht3, A2, Gt3, KK2, KK2, 1, dinv3, b3);
    score_topk_pool<<<B64, 256, 0, stream>>>(Gt3, p3, pnorm + 2, idx3, nullptr, R,
                                             KK2, KK3, 0, 0);

    // fused MLP head
    head_fused<<<B64, 256, 0, stream>>>(seq, tf_w, tf_b, R, cat_w, cat_b, w1_gate,
                                        fc1_w, fc1_b, fc2_w, fc2_b, out_w, out_b,
                                        out);
}